// Round 11
// baseline (307.607 us; speedup 1.0000x reference)
//
#include <hip/hip_runtime.h>

// Problem constants (match reference)
#define HH 256
#define WW 256
#define NB 2
#define NN 128
#define NSTEPS_K 50
#define NBLK 256                 // one block per CU -> co-residency guaranteed
#define MAGIC_G 0x11C0FFEE
#define MAGIC_E 0x22C0FFEE
#define MAGIC_R 0x33C0FFEE
#define SPIN_CAP 5000000         // safety: never triggers in correct operation

// ws layout (floats):
//   [0 .. 255]     partials (1 per block)
//   [256 .. 511]   g_flags  (int, per-block grad-done)
//   [512 .. 767]   r_flags  (int, per-block render-done)
//   [768 .. 769]   e_flags  (int, per-batch evolve-done)
//   [1024 .. 1535] fnodes
//   [2048 .. ]     gradient field: NB*HH*WW float2 (512KB/batch)
//   (all flags are reset to 0 in-kernel at the end of every call; the magic
//    values differ from the harness 0xAA poison, so every replay orders
//    correctly without a separate memset dispatch)
#define WS_GRAD_OFF_F 2048
#define WS_NEEDED_BYTES ((WS_GRAD_OFF_F + (size_t)NB * HH * WW * 2) * 4)

__global__ __launch_bounds__(1024) void fused_kernel(
        const float* __restrict__ pred,
        const float* __restrict__ nodes_in,
        float* __restrict__ ws,
        float* __restrict__ out) {
    float* partials = ws;
    int*   g_flags  = (int*)(ws + 256);
    int*   r_flags  = (int*)(ws + 512);
    int*   e_flags  = (int*)(ws + 768);
    float* fnodes   = ws + 1024;
    float2* g       = (float2*)(ws + WS_GRAD_OFF_F);

    const int blk = blockIdx.x;     // 0..255
    const int tid = threadIdx.x;    // 0..1023

    // ================= Phase 1: gradient field (512 cells/block) =============
    if (tid < 512) {
        int idx = blk * 512 + tid;          // 0 .. 131071
        int b = idx >> 16, p = idx & 0xFFFF;
        int i = p >> 8, j = p & (WW - 1);
        const float* f = pred + (b << 16);
        int iu = max(i - 1, 0), id = min(i + 1, HH - 1);
        int jl = max(j - 1, 0), jr = min(j + 1, WW - 1);
        float sy = (i == 0 || i == HH - 1) ? 1.0f : 0.5f;
        float sx = (j == 0 || j == WW - 1) ? 1.0f : 0.5f;
        g[idx] = make_float2(sy * (f[(id << 8) + j] - f[(iu << 8) + j]),
                             sx * (f[(i << 8) + jr] - f[(i << 8) + jl]));
    }
    __syncthreads();
    if (tid == 0) {
        __threadfence();   // publish this block's field slice (L2 writeback)
        __hip_atomic_store(&g_flags[blk], MAGIC_G, __ATOMIC_RELEASE, __HIP_MEMORY_SCOPE_AGENT);
    }

    // ================= Phase 2: evolve (blocks 0..NB-1) ======================
    if (blk < NB) {
        if (tid < 64) {   // wave 0 polls all 256 grad flags (4 per lane)
            for (int it = 0; it < SPIN_CAP; ++it) {
                int a0 = __hip_atomic_load(&g_flags[tid*4+0], __ATOMIC_ACQUIRE, __HIP_MEMORY_SCOPE_AGENT);
                int a1 = __hip_atomic_load(&g_flags[tid*4+1], __ATOMIC_ACQUIRE, __HIP_MEMORY_SCOPE_AGENT);
                int a2 = __hip_atomic_load(&g_flags[tid*4+2], __ATOMIC_ACQUIRE, __HIP_MEMORY_SCOPE_AGENT);
                int a3 = __hip_atomic_load(&g_flags[tid*4+3], __ATOMIC_ACQUIRE, __HIP_MEMORY_SCOPE_AGENT);
                bool ok = (a0 == MAGIC_G) && (a1 == MAGIC_G) && (a2 == MAGIC_G) && (a3 == MAGIC_G);
                if (__all(ok)) break;
                __builtin_amdgcn_s_sleep(8);
            }
        }
        __syncthreads();
        (void)__hip_atomic_load(&g_flags[0], __ATOMIC_ACQUIRE, __HIP_MEMORY_SCOPE_AGENT);

        const int b = blk;
        const float2* gb = g + (b << 16);

        // ---- warm this batch's 512KB field into the LOCAL XCD L2 (R7 win) ----
        float acc = 0.0f;
        #pragma unroll
        for (int k = 0; k < 8; ++k) acc += gb[((k << 10) + tid) << 3].x;
        asm volatile("" :: "v"(acc));
        __syncthreads();

        if (tid < 64) {
            const int l = tid;
            const int pl = (l + 63) & 63;
            const int nl = (l + 1) & 63;
            float4 nd = ((const float4*)nodes_in)[b * 64 + l];
            float y0n = nd.x, x0n = nd.y;      // node 2l
            float y1n = nd.z, x1n = nd.w;      // node 2l+1

            __builtin_amdgcn_s_setprio(1);
            for (int s = 0; s < NSTEPS_K; ++s) {
                // bilerp loads first (8 x dwordx2, warm L1/L2 hits)
                float yca = fminf(fmaxf(y0n, 0.0f), 254.999f);
                float xca = fminf(fmaxf(x0n, 0.0f), 254.999f);
                int ra = (int)yca, ca = (int)xca;
                float wya = yca - (float)ra, wxa = xca - (float)ca;
                int basea = (ra << 8) + ca;
                float2 a00 = gb[basea],       a01 = gb[basea + 1];
                float2 a10 = gb[basea + WW],  a11 = gb[basea + WW + 1];

                float ycb = fminf(fmaxf(y1n, 0.0f), 254.999f);
                float xcb = fminf(fmaxf(x1n, 0.0f), 254.999f);
                int rb = (int)ycb, cb = (int)xcb;
                float wyb = ycb - (float)rb, wxb = xcb - (float)cb;
                int baseb = (rb << 8) + cb;
                float2 b00 = gb[baseb],       b01 = gb[baseb + 1];
                float2 b10 = gb[baseb + WW],  b11 = gb[baseb + WW + 1];

                // single shuffle round: neighbor positions
                float pya = __shfl(y0n, pl), pxa = __shfl(x0n, pl);
                float pyb = __shfl(y1n, pl), pxb = __shfl(x1n, pl);
                float nya = __shfl(y0n, nl), nxa = __shfl(x0n, nl);
                float nyb = __shfl(y1n, nl), nxb = __shfl(x1n, nl);

                // d2[i] = (x[i+1] + x[i-1]) - 2 x[i]
                float d2ya = (y1n + pyb) - 2.0f * y0n;
                float d2xa = (x1n + pxb) - 2.0f * x0n;
                float d2yb = (nya + y0n) - 2.0f * y1n;
                float d2xb = (nxa + x0n) - 2.0f * x1n;
                float d2pyb = (y0n + pya) - 2.0f * pyb;
                float d2pxb = (x0n + pxa) - 2.0f * pxb;
                float d2nya = (nyb + y1n) - 2.0f * nya;
                float d2nxa = (nxb + x1n) - 2.0f * nxa;

                // d4[i] = (d2[i+1] + d2[i-1]) - 2 d2[i]
                float d4ya = (d2yb + d2pyb) - 2.0f * d2ya;
                float d4xa = (d2xb + d2pxb) - 2.0f * d2xa;
                float d4yb = (d2nya + d2ya) - 2.0f * d2yb;
                float d4xb = (d2nxa + d2xa) - 2.0f * d2xb;

                // bilerp (reference term order)
                float ua = 1.0f - wya, va = 1.0f - wxa;
                float bya = a00.x * ua * va + a01.x * ua * wxa + a10.x * wya * va + a11.x * wya * wxa;
                float bxa = a00.y * ua * va + a01.y * ua * wxa + a10.y * wya * va + a11.y * wya * wxa;
                float ub = 1.0f - wyb, vb = 1.0f - wxb;
                float byb = b00.x * ub * vb + b01.x * ub * wxb + b10.x * wyb * vb + b11.x * wyb * wxb;
                float bxb = b00.y * ub * vb + b01.y * ub * wxb + b10.y * wyb * vb + b11.y * wyb * wxb;

                // x += STEPSZ*(ALPHA*d2 - BETA*d4 + ext); clip [0,255]
                y0n = y0n + 0.1f * ((0.01f * d2ya - 0.01f * d4ya) + (-10.0f * bya));
                x0n = x0n + 0.1f * ((0.01f * d2xa - 0.01f * d4xa) + (-10.0f * bxa));
                y1n = y1n + 0.1f * ((0.01f * d2yb - 0.01f * d4yb) + (-10.0f * byb));
                x1n = x1n + 0.1f * ((0.01f * d2xb - 0.01f * d4xb) + (-10.0f * bxb));
                y0n = fminf(fmaxf(y0n, 0.0f), 255.0f);
                x0n = fminf(fmaxf(x0n, 0.0f), 255.0f);
                y1n = fminf(fmaxf(y1n, 0.0f), 255.0f);
                x1n = fminf(fmaxf(x1n, 0.0f), 255.0f);
            }
            __builtin_amdgcn_s_setprio(0);

            float4 o4; o4.x = y0n; o4.y = x0n; o4.z = y1n; o4.w = x1n;
            ((float4*)fnodes)[b * 64 + l] = o4;
            if (l == 0) {
                __threadfence();   // publish fnodes (wave-level waitcnt + wbl2)
                __hip_atomic_store(&e_flags[b], MAGIC_E, __ATOMIC_RELEASE, __HIP_MEMORY_SCOPE_AGENT);
            }
        }
        __syncthreads();
    }

    // ================= all blocks wait for both evolve flags ==================
    if (tid == 0) {
        for (int it = 0; it < SPIN_CAP; ++it) {
            int e0 = __hip_atomic_load(&e_flags[0], __ATOMIC_ACQUIRE, __HIP_MEMORY_SCOPE_AGENT);
            int e1 = __hip_atomic_load(&e_flags[1], __ATOMIC_ACQUIRE, __HIP_MEMORY_SCOPE_AGENT);
            if (e0 == MAGIC_E && e1 == MAGIC_E) break;
            __builtin_amdgcn_s_sleep(16);
        }
    }
    __syncthreads();
    (void)__hip_atomic_load(&e_flags[0], __ATOMIC_ACQUIRE, __HIP_MEMORY_SCOPE_AGENT);

    // ================= Phase 3: render (512 px/block) =========================
    __shared__ float p0y[2 * NN], p0x[2 * NN], sdy[2 * NN], sdx[2 * NN], sidd[2 * NN];
    if (tid < 2 * NN) {
        int b = tid >> 7, node = tid & (NN - 1);
        const float* fb = fnodes + b * 2 * NN;
        float ay = fb[node * 2], ax = fb[node * 2 + 1];
        int nx = (node + 1) & (NN - 1);
        float cy = fb[nx * 2], cx = fb[nx * 2 + 1];
        float ddy = cy - ay, ddx = cx - ax;
        p0y[tid] = ay; p0x[tid] = ax;
        sdy[tid] = ddy; sdx[tid] = ddx;
        sidd[tid] = 1.0f / (ddy * ddy + ddx * ddx + 1e-8f);
    }
    __syncthreads();

    float se = 0.0f;
    if (tid < 512) {
        int px = blk * 512 + tid;           // 0 .. 131071
        int b = px >> 16;
        int pp = px & 0xFFFF;
        float qy = (float)(pp >> 8);
        float qx = (float)(pp & (WW - 1));
        const int base = b << 7;
        float minr2 = 1e30f;
        #pragma unroll 8
        for (int s = 0; s < NN; ++s) {
            float qpy = qy - p0y[base + s];
            float qpx = qx - p0x[base + s];
            float t = (qpy * sdy[base + s] + qpx * sdx[base + s]) * sidd[base + s];
            t = fminf(fmaxf(t, 0.0f), 1.0f);
            float ry = qpy - t * sdy[base + s];
            float rx = qpx - t * sdx[base + s];
            minr2 = fminf(minr2, ry * ry + rx * rx);
        }
        float dist = fminf(sqrtf(minr2 + 1e-12f), 15.0f);
        float e = pred[px] - dist;
        se = e * e;
    }
    for (int off = 32; off > 0; off >>= 1) se += __shfl_down(se, off);
    __shared__ float red[16];
    if ((tid & 63) == 0) red[tid >> 6] = se;   // waves 8..15 write 0
    __syncthreads();
    if (tid == 0) {
        float p = 0.0f;
        #pragma unroll
        for (int w = 0; w < 8; ++w) p += red[w];
        __hip_atomic_store(&partials[blk], p, __ATOMIC_RELEASE, __HIP_MEMORY_SCOPE_AGENT);
        __hip_atomic_store(&r_flags[blk], MAGIC_R, __ATOMIC_RELEASE, __HIP_MEMORY_SCOPE_AGENT);
    }

    // ================= Phase 4: finalize + flag reset (block 0) ===============
    if (blk == 0 && tid < 64) {
        for (int it = 0; it < SPIN_CAP; ++it) {
            int a0 = __hip_atomic_load(&r_flags[tid*4+0], __ATOMIC_ACQUIRE, __HIP_MEMORY_SCOPE_AGENT);
            int a1 = __hip_atomic_load(&r_flags[tid*4+1], __ATOMIC_ACQUIRE, __HIP_MEMORY_SCOPE_AGENT);
            int a2 = __hip_atomic_load(&r_flags[tid*4+2], __ATOMIC_ACQUIRE, __HIP_MEMORY_SCOPE_AGENT);
            int a3 = __hip_atomic_load(&r_flags[tid*4+3], __ATOMIC_ACQUIRE, __HIP_MEMORY_SCOPE_AGENT);
            bool ok = (a0 == MAGIC_R) && (a1 == MAGIC_R) && (a2 == MAGIC_R) && (a3 == MAGIC_R);
            if (__all(ok)) break;
            __builtin_amdgcn_s_sleep(8);
        }
        float s = 0.0f;
        #pragma unroll
        for (int k = 0; k < 4; ++k)   // fixed order -> deterministic
            s += __hip_atomic_load(&partials[tid + (k << 6)], __ATOMIC_RELAXED, __HIP_MEMORY_SCOPE_AGENT);
        for (int off = 32; off > 0; off >>= 1) s += __shfl_down(s, off);
        if (tid == 0) out[0] = s * (1.0f / (float)(NB * HH * WW));
        // reset all flags for the next replay (everyone is past their last read)
        #pragma unroll
        for (int k = 0; k < 4; ++k) { g_flags[tid*4+k] = 0; r_flags[tid*4+k] = 0; }
        if (tid == 0) { e_flags[0] = 0; e_flags[1] = 0; }
    }
}

// ---------------- fallback (ws too small): R2-style 3-phase ------------------
__device__ __forceinline__ void sample_grad_direct(const float* __restrict__ f,
                                                   float y, float x,
                                                   float& by, float& bx) {
    float yc = fminf(fmaxf(y, 0.0f), 254.999f);
    float xc = fminf(fmaxf(x, 0.0f), 254.999f);
    int r0 = (int)yc, c0 = (int)xc;
    int r1 = r0 + 1, c1 = c0 + 1;
    float wy = yc - (float)r0, wx = xc - (float)c0;
    int rm = max(r0 - 1, 0), rp = min(r1 + 1, HH - 1);
    int cm = max(c0 - 1, 0), cp = min(c1 + 1, WW - 1);
    float sy0 = (r0 == 0) ? 1.0f : 0.5f;
    float sy1 = (r1 == HH - 1) ? 1.0f : 0.5f;
    float sx0 = (c0 == 0) ? 1.0f : 0.5f;
    float sx1 = (c1 == WW - 1) ? 1.0f : 0.5f;
    const float* fr0 = f + (r0 << 8);
    const float* fr1 = f + (r1 << 8);
    const float* frm = f + (rm << 8);
    const float* frp = f + (rp << 8);
    float f00 = fr0[c0], f01 = fr0[c1];
    float f10 = fr1[c0], f11 = fr1[c1];
    float f0m = fr0[cm], f0p = fr0[cp];
    float f1m = fr1[cm], f1p = fr1[cp];
    float fm0 = frm[c0], fm1 = frm[c1];
    float fp0 = frp[c0], fp1 = frp[c1];
    float gy00 = sy0 * (f10 - fm0), gy01 = sy0 * (f11 - fm1);
    float gy10 = sy1 * (fp0 - f00), gy11 = sy1 * (fp1 - f01);
    float gx00 = sx0 * (f01 - f0m), gx01 = sx1 * (f0p - f00);
    float gx10 = sx0 * (f11 - f1m), gx11 = sx1 * (f1p - f10);
    float u = 1.0f - wy, v = 1.0f - wx;
    by = gy00 * u * v + gy01 * u * wx + gy10 * wy * v + gy11 * wy * wx;
    bx = gx00 * u * v + gx01 * u * wx + gx10 * wy * v + gx11 * wy * wx;
}

__global__ __launch_bounds__(64, 1) void evolve_direct_kernel(
        const float* __restrict__ pred,
        const float* __restrict__ nodes_in,
        float* __restrict__ nodes_out,
        int* __restrict__ counter) {
    const int b = blockIdx.x;
    const int l = threadIdx.x;
    if (b == 0 && l == 0)
        __hip_atomic_store(counter, 0, __ATOMIC_RELAXED, __HIP_MEMORY_SCOPE_AGENT);
    const float* f = pred + b * HH * WW;
    const int pl = (l + 63) & 63;
    const int nl = (l + 1) & 63;
    float4 nd = ((const float4*)nodes_in)[b * 64 + l];
    float y0n = nd.x, x0n = nd.y, y1n = nd.z, x1n = nd.w;
    for (int s = 0; s < NSTEPS_K; ++s) {
        float by0, bx0, by1, bx1;
        sample_grad_direct(f, y0n, x0n, by0, bx0);
        sample_grad_direct(f, y1n, x1n, by1, bx1);
        float pya = __shfl(y0n, pl), pxa = __shfl(x0n, pl);
        float pyb = __shfl(y1n, pl), pxb = __shfl(x1n, pl);
        float nya = __shfl(y0n, nl), nxa = __shfl(x0n, nl);
        float nyb = __shfl(y1n, nl), nxb = __shfl(x1n, nl);
        float d2ya = (y1n + pyb) - 2.0f * y0n;
        float d2xa = (x1n + pxb) - 2.0f * x0n;
        float d2yb = (nya + y0n) - 2.0f * y1n;
        float d2xb = (nxa + x0n) - 2.0f * x1n;
        float d2pyb = (y0n + pya) - 2.0f * pyb;
        float d2pxb = (x0n + pxa) - 2.0f * pxb;
        float d2nya = (nyb + y1n) - 2.0f * nya;
        float d2nxa = (nxb + x1n) - 2.0f * nxa;
        float d4ya = (d2yb + d2pyb) - 2.0f * d2ya;
        float d4xa = (d2xb + d2pxb) - 2.0f * d2xa;
        float d4yb = (d2nya + d2ya) - 2.0f * d2yb;
        float d4xb = (d2nxa + d2xa) - 2.0f * d2xb;
        y0n = y0n + 0.1f * ((0.01f * d2ya - 0.01f * d4ya) + (-10.0f * by0));
        x0n = x0n + 0.1f * ((0.01f * d2xa - 0.01f * d4xa) + (-10.0f * bx0));
        y1n = y1n + 0.1f * ((0.01f * d2yb - 0.01f * d4yb) + (-10.0f * by1));
        x1n = x1n + 0.1f * ((0.01f * d2xb - 0.01f * d4xb) + (-10.0f * bx1));
        y0n = fminf(fmaxf(y0n, 0.0f), 255.0f);
        x0n = fminf(fmaxf(x0n, 0.0f), 255.0f);
        y1n = fminf(fmaxf(y1n, 0.0f), 255.0f);
        x1n = fminf(fmaxf(x1n, 0.0f), 255.0f);
    }
    float4 o4; o4.x = y0n; o4.y = x0n; o4.z = y1n; o4.w = x1n;
    ((float4*)nodes_out)[b * 64 + l] = o4;
}

#define RBLK ((HH * WW) / 256)
#define NPART (NB * RBLK)

__global__ void render_kernel(const float* __restrict__ pred,
                              const float* __restrict__ nodes,
                              float* __restrict__ partials,
                              int* __restrict__ counter,
                              float* __restrict__ out) {
    const int b = blockIdx.y;
    const int chunk = blockIdx.x;
    const int tid = threadIdx.x;
    __shared__ float p0y[NN], p0x[NN], sdy[NN], sdx[NN], sidd[NN];
    if (tid < NN) {
        float ay = nodes[(b * NN + tid) * 2 + 0];
        float ax = nodes[(b * NN + tid) * 2 + 1];
        int j = (tid + 1) & (NN - 1);
        float cy = nodes[(b * NN + j) * 2 + 0];
        float cx = nodes[(b * NN + j) * 2 + 1];
        float ddy = cy - ay, ddx = cx - ax;
        p0y[tid] = ay; p0x[tid] = ax;
        sdy[tid] = ddy; sdx[tid] = ddx;
        sidd[tid] = 1.0f / (ddy * ddy + ddx * ddx + 1e-8f);
    }
    __syncthreads();
    const int pix = chunk * 256 + tid;
    const float qy = (float)(pix >> 8);
    const float qx = (float)(pix & (WW - 1));
    float minr2 = 1e30f;
#pragma unroll 8
    for (int s = 0; s < NN; ++s) {
        float qpy = qy - p0y[s];
        float qpx = qx - p0x[s];
        float t = (qpy * sdy[s] + qpx * sdx[s]) * sidd[s];
        t = fminf(fmaxf(t, 0.0f), 1.0f);
        float ry = qpy - t * sdy[s];
        float rx = qpx - t * sdx[s];
        minr2 = fminf(minr2, ry * ry + rx * rx);
    }
    float dist = fminf(sqrtf(minr2 + 1e-12f), 15.0f);
    float e = pred[b * HH * WW + pix] - dist;
    float se = e * e;
    for (int off = 32; off > 0; off >>= 1) se += __shfl_down(se, off);
    __shared__ float red[4];
    if ((tid & 63) == 0) red[tid >> 6] = se;
    __syncthreads();
    __shared__ int lastBlk;
    if (tid == 0) {
        float p = (red[0] + red[1]) + (red[2] + red[3]);
        __hip_atomic_store(&partials[b * RBLK + chunk], p, __ATOMIC_RELEASE, __HIP_MEMORY_SCOPE_AGENT);
        int t = __hip_atomic_fetch_add(counter, 1, __ATOMIC_ACQ_REL, __HIP_MEMORY_SCOPE_AGENT);
        lastBlk = (t == NPART - 1);
    }
    __syncthreads();
    if (lastBlk) {
        float v = __hip_atomic_load(&partials[tid], __ATOMIC_RELAXED, __HIP_MEMORY_SCOPE_AGENT)
                + __hip_atomic_load(&partials[tid + 256], __ATOMIC_RELAXED, __HIP_MEMORY_SCOPE_AGENT);
        for (int off = 32; off > 0; off >>= 1) v += __shfl_down(v, off);
        __shared__ float red2[4];
        if ((tid & 63) == 0) red2[tid >> 6] = v;
        __syncthreads();
        if (tid == 0)
            out[0] = ((red2[0] + red2[1]) + (red2[2] + red2[3])) * (1.0f / (float)(NB * HH * WW));
    }
}

extern "C" void kernel_launch(void* const* d_in, const int* in_sizes, int n_in,
                              void* d_out, int out_size, void* d_ws, size_t ws_size,
                              hipStream_t stream) {
    const float* pred = (const float*)d_in[0];    // (B,1,H,W) f32
    const float* nodes = (const float*)d_in[1];   // (B,N,2) f32
    float* ws = (float*)d_ws;

    if (ws_size >= WS_NEEDED_BYTES) {
        fused_kernel<<<dim3(NBLK), dim3(1024), 0, stream>>>(pred, nodes, ws, (float*)d_out);
    } else {
        // fallback: 2-kernel path (no gradient field buffer)
        float* partials = ws;                  // 512 f
        float* fnodes = ws + 512;              // 512 f
        int* counter = (int*)(ws + 1024);
        evolve_direct_kernel<<<dim3(NB), dim3(64), 0, stream>>>(pred, nodes, fnodes, counter);
        render_kernel<<<dim3(RBLK, NB), dim3(256), 0, stream>>>(pred, fnodes, partials,
                                                                counter, (float*)d_out);
    }
}

// Round 12
// 84.959 us; speedup vs baseline: 3.6207x; 3.6207x over previous
//
#include <hip/hip_runtime.h>

// Problem constants (match reference)
#define HH 256
#define WW 256
#define NB 2
#define NN 128
#define NSTEPS_K 50
#define NBLK 256                 // one block per CU -> co-residency guaranteed
#define MAGIC_G 0x11C0FFEE
#define MAGIC_E 0x22C0FFEE
#define MAGIC_R 0x33C0FFEE
#define SPIN_CAP 200000          // safety bound; never triggers in correct runs

// ws layout (floats):
//   [0 .. 255]     partials (1 per block)
//   [256 .. 511]   g_flags  (int, per-block grad-done)
//   [512 .. 767]   r_flags  (int, per-block render-done)
//   [768 .. 769]   e_flags  (int, per-batch evolve-done)
//   [1024 .. 1535] fnodes
//   [2048 .. ]     gradient field: NB*HH*WW float2 (512KB/batch)
// Flags use magic values (!= 0xAAAAAAAA poison) and are reset via coherent
// atomic stores at the end of each call -> every replay orders correctly.
#define WS_GRAD_OFF_F 2048
#define WS_NEEDED_BYTES ((WS_GRAD_OFF_F + (size_t)NB * HH * WW * 2) * 4)

__device__ __forceinline__ int ld_rlx(int* p) {
    return __hip_atomic_load(p, __ATOMIC_RELAXED, __HIP_MEMORY_SCOPE_AGENT);
}
__device__ __forceinline__ int ld_acq(int* p) {   // ONE invalidate, post-poll only
    return __hip_atomic_load(p, __ATOMIC_ACQUIRE, __HIP_MEMORY_SCOPE_AGENT);
}
__device__ __forceinline__ void st_rel(int* p, int v) {
    __hip_atomic_store(p, v, __ATOMIC_RELEASE, __HIP_MEMORY_SCOPE_AGENT);
}
__device__ __forceinline__ void st_rlx(int* p, int v) {
    __hip_atomic_store(p, v, __ATOMIC_RELAXED, __HIP_MEMORY_SCOPE_AGENT);
}

__global__ __launch_bounds__(1024) void fused_kernel(
        const float* __restrict__ pred,
        const float* __restrict__ nodes_in,
        float* __restrict__ ws,
        float* __restrict__ out) {
    float* partials = ws;
    int*   g_flags  = (int*)(ws + 256);
    int*   r_flags  = (int*)(ws + 512);
    int*   e_flags  = (int*)(ws + 768);
    float* fnodes   = ws + 1024;
    float2* g       = (float2*)(ws + WS_GRAD_OFF_F);

    const int blk = blockIdx.x;     // 0..255
    const int tid = threadIdx.x;    // 0..1023

    // ================= Phase 1: gradient field (512 cells/block) =============
    if (tid < 512) {
        int idx = blk * 512 + tid;          // 0 .. 131071
        int b = idx >> 16, p = idx & 0xFFFF;
        int i = p >> 8, j = p & (WW - 1);
        const float* f = pred + (b << 16);
        int iu = max(i - 1, 0), id = min(i + 1, HH - 1);
        int jl = max(j - 1, 0), jr = min(j + 1, WW - 1);
        float sy = (i == 0 || i == HH - 1) ? 1.0f : 0.5f;
        float sx = (j == 0 || j == WW - 1) ? 1.0f : 0.5f;
        g[idx] = make_float2(sy * (f[(id << 8) + j] - f[(iu << 8) + j]),
                             sx * (f[(i << 8) + jr] - f[(i << 8) + jl]));
    }
    __syncthreads();
    if (tid == 0) st_rel(&g_flags[blk], MAGIC_G);   // release = wbL2 + publish

    // ================= Phase 2: evolve (blocks 0..NB-1) ======================
    if (blk < NB) {
        if (tid < 64) {   // wave 0: RELAXED poll of all 256 grad flags (4/lane)
            for (int it = 0; it < SPIN_CAP; ++it) {
                bool ok = (ld_rlx(&g_flags[tid*4+0]) == MAGIC_G) &&
                          (ld_rlx(&g_flags[tid*4+1]) == MAGIC_G) &&
                          (ld_rlx(&g_flags[tid*4+2]) == MAGIC_G) &&
                          (ld_rlx(&g_flags[tid*4+3]) == MAGIC_G);
                if (__all(ok)) break;
                __builtin_amdgcn_s_sleep(8);
            }
        }
        __syncthreads();
        (void)ld_acq(&g_flags[0]);   // single invalidate for ALL waves' loads

        const int b = blk;
        const float2* gb = g + (b << 16);

        // ---- warm this batch's 512KB field into the LOCAL XCD L2 (R7 win) ----
        float acc = 0.0f;
        #pragma unroll
        for (int k = 0; k < 8; ++k) acc += gb[((k << 10) + tid) << 3].x;
        asm volatile("" :: "v"(acc));
        __syncthreads();

        if (tid < 64) {
            const int l = tid;
            const int pl = (l + 63) & 63;
            const int nl = (l + 1) & 63;
            float4 nd = ((const float4*)nodes_in)[b * 64 + l];
            float y0n = nd.x, x0n = nd.y;      // node 2l
            float y1n = nd.z, x1n = nd.w;      // node 2l+1

            __builtin_amdgcn_s_setprio(1);
            for (int s = 0; s < NSTEPS_K; ++s) {
                // bilerp loads first (8 x dwordx2, warm L1/L2 hits)
                float yca = fminf(fmaxf(y0n, 0.0f), 254.999f);
                float xca = fminf(fmaxf(x0n, 0.0f), 254.999f);
                int ra = (int)yca, ca = (int)xca;
                float wya = yca - (float)ra, wxa = xca - (float)ca;
                int basea = (ra << 8) + ca;
                float2 a00 = gb[basea],       a01 = gb[basea + 1];
                float2 a10 = gb[basea + WW],  a11 = gb[basea + WW + 1];

                float ycb = fminf(fmaxf(y1n, 0.0f), 254.999f);
                float xcb = fminf(fmaxf(x1n, 0.0f), 254.999f);
                int rb = (int)ycb, cb = (int)xcb;
                float wyb = ycb - (float)rb, wxb = xcb - (float)cb;
                int baseb = (rb << 8) + cb;
                float2 b00 = gb[baseb],       b01 = gb[baseb + 1];
                float2 b10 = gb[baseb + WW],  b11 = gb[baseb + WW + 1];

                // single shuffle round: neighbor positions
                float pya = __shfl(y0n, pl), pxa = __shfl(x0n, pl);
                float pyb = __shfl(y1n, pl), pxb = __shfl(x1n, pl);
                float nya = __shfl(y0n, nl), nxa = __shfl(x0n, nl);
                float nyb = __shfl(y1n, nl), nxb = __shfl(x1n, nl);

                // d2[i] = (x[i+1] + x[i-1]) - 2 x[i]
                float d2ya = (y1n + pyb) - 2.0f * y0n;
                float d2xa = (x1n + pxb) - 2.0f * x0n;
                float d2yb = (nya + y0n) - 2.0f * y1n;
                float d2xb = (nxa + x0n) - 2.0f * x1n;
                float d2pyb = (y0n + pya) - 2.0f * pyb;
                float d2pxb = (x0n + pxa) - 2.0f * pxb;
                float d2nya = (nyb + y1n) - 2.0f * nya;
                float d2nxa = (nxb + x1n) - 2.0f * nxa;

                // d4[i] = (d2[i+1] + d2[i-1]) - 2 d2[i]
                float d4ya = (d2yb + d2pyb) - 2.0f * d2ya;
                float d4xa = (d2xb + d2pxb) - 2.0f * d2xa;
                float d4yb = (d2nya + d2ya) - 2.0f * d2yb;
                float d4xb = (d2nxa + d2xa) - 2.0f * d2xb;

                // bilerp (reference term order)
                float ua = 1.0f - wya, va = 1.0f - wxa;
                float bya = a00.x * ua * va + a01.x * ua * wxa + a10.x * wya * va + a11.x * wya * wxa;
                float bxa = a00.y * ua * va + a01.y * ua * wxa + a10.y * wya * va + a11.y * wya * wxa;
                float ub = 1.0f - wyb, vb = 1.0f - wxb;
                float byb = b00.x * ub * vb + b01.x * ub * wxb + b10.x * wyb * vb + b11.x * wyb * wxb;
                float bxb = b00.y * ub * vb + b01.y * ub * wxb + b10.y * wyb * vb + b11.y * wyb * wxb;

                // x += STEPSZ*(ALPHA*d2 - BETA*d4 + ext); clip [0,255]
                y0n = y0n + 0.1f * ((0.01f * d2ya - 0.01f * d4ya) + (-10.0f * bya));
                x0n = x0n + 0.1f * ((0.01f * d2xa - 0.01f * d4xa) + (-10.0f * bxa));
                y1n = y1n + 0.1f * ((0.01f * d2yb - 0.01f * d4yb) + (-10.0f * byb));
                x1n = x1n + 0.1f * ((0.01f * d2xb - 0.01f * d4xb) + (-10.0f * bxb));
                y0n = fminf(fmaxf(y0n, 0.0f), 255.0f);
                x0n = fminf(fmaxf(x0n, 0.0f), 255.0f);
                y1n = fminf(fmaxf(y1n, 0.0f), 255.0f);
                x1n = fminf(fmaxf(x1n, 0.0f), 255.0f);
            }
            __builtin_amdgcn_s_setprio(0);

            float4 o4; o4.x = y0n; o4.y = x0n; o4.z = y1n; o4.w = x1n;
            ((float4*)fnodes)[b * 64 + l] = o4;
            if (l == 0) st_rel(&e_flags[b], MAGIC_E);   // wbL2 + publish fnodes
        }
        __syncthreads();
    }

    // ============ all blocks wait for both evolve flags (RELAXED poll) ========
    if (tid == 0) {
        for (int it = 0; it < SPIN_CAP; ++it) {
            if (ld_rlx(&e_flags[0]) == MAGIC_E && ld_rlx(&e_flags[1]) == MAGIC_E) break;
            __builtin_amdgcn_s_sleep(16);
        }
    }
    __syncthreads();
    (void)ld_acq(&e_flags[0]);   // single invalidate before reading fnodes

    // ================= Phase 3: render (512 px/block) =========================
    __shared__ float p0y[2 * NN], p0x[2 * NN], sdy[2 * NN], sdx[2 * NN], sidd[2 * NN];
    if (tid < 2 * NN) {
        int b = tid >> 7, node = tid & (NN - 1);
        const float* fb = fnodes + b * 2 * NN;
        float ay = fb[node * 2], ax = fb[node * 2 + 1];
        int nx = (node + 1) & (NN - 1);
        float cy = fb[nx * 2], cx = fb[nx * 2 + 1];
        float ddy = cy - ay, ddx = cx - ax;
        p0y[tid] = ay; p0x[tid] = ax;
        sdy[tid] = ddy; sdx[tid] = ddx;
        sidd[tid] = 1.0f / (ddy * ddy + ddx * ddx + 1e-8f);
    }
    __syncthreads();

    float se = 0.0f;
    if (tid < 512) {
        int px = blk * 512 + tid;           // 0 .. 131071
        int b = px >> 16;
        int pp = px & 0xFFFF;
        float qy = (float)(pp >> 8);
        float qx = (float)(pp & (WW - 1));
        const int base = b << 7;
        float minr2 = 1e30f;
        #pragma unroll 8
        for (int s = 0; s < NN; ++s) {
            float qpy = qy - p0y[base + s];
            float qpx = qx - p0x[base + s];
            float t = (qpy * sdy[base + s] + qpx * sdx[base + s]) * sidd[base + s];
            t = fminf(fmaxf(t, 0.0f), 1.0f);
            float ry = qpy - t * sdy[base + s];
            float rx = qpx - t * sdx[base + s];
            minr2 = fminf(minr2, ry * ry + rx * rx);
        }
        float dist = fminf(sqrtf(minr2 + 1e-12f), 15.0f);
        float e = pred[px] - dist;
        se = e * e;
    }
    for (int off = 32; off > 0; off >>= 1) se += __shfl_down(se, off);
    __shared__ float red[16];
    if ((tid & 63) == 0) red[tid >> 6] = se;   // waves 8..15 write 0
    __syncthreads();
    if (tid == 0) {
        float p = 0.0f;
        #pragma unroll
        for (int w = 0; w < 8; ++w) p += red[w];
        __hip_atomic_store(&partials[blk], p, __ATOMIC_RELEASE, __HIP_MEMORY_SCOPE_AGENT);
        st_rel(&r_flags[blk], MAGIC_R);
    }

    // ================= Phase 4: finalize + flag reset (block 0) ===============
    if (blk == 0 && tid < 64) {
        for (int it = 0; it < SPIN_CAP; ++it) {   // RELAXED poll (4 flags/lane)
            bool ok = (ld_rlx(&r_flags[tid*4+0]) == MAGIC_R) &&
                      (ld_rlx(&r_flags[tid*4+1]) == MAGIC_R) &&
                      (ld_rlx(&r_flags[tid*4+2]) == MAGIC_R) &&
                      (ld_rlx(&r_flags[tid*4+3]) == MAGIC_R);
            if (__all(ok)) break;
            __builtin_amdgcn_s_sleep(8);
        }
        (void)ld_acq(&r_flags[0]);   // single invalidate
        float s = 0.0f;
        #pragma unroll
        for (int k = 0; k < 4; ++k)   // fixed order -> deterministic
            s += __hip_atomic_load(&partials[tid + (k << 6)], __ATOMIC_RELAXED,
                                   __HIP_MEMORY_SCOPE_AGENT);
        for (int off = 32; off > 0; off >>= 1) s += __shfl_down(s, off);
        if (tid == 0) out[0] = s * (1.0f / (float)(NB * HH * WW));
        // reset flags via coherent atomic stores (visible to next replay's polls)
        #pragma unroll
        for (int k = 0; k < 4; ++k) { st_rlx(&g_flags[tid*4+k], 0); st_rlx(&r_flags[tid*4+k], 0); }
        if (tid == 0) { st_rlx(&e_flags[0], 0); st_rlx(&e_flags[1], 0); }
    }
}

// ---------------- fallback (ws too small): 2-kernel path ---------------------
__device__ __forceinline__ void sample_grad_direct(const float* __restrict__ f,
                                                   float y, float x,
                                                   float& by, float& bx) {
    float yc = fminf(fmaxf(y, 0.0f), 254.999f);
    float xc = fminf(fmaxf(x, 0.0f), 254.999f);
    int r0 = (int)yc, c0 = (int)xc;
    int r1 = r0 + 1, c1 = c0 + 1;
    float wy = yc - (float)r0, wx = xc - (float)c0;
    int rm = max(r0 - 1, 0), rp = min(r1 + 1, HH - 1);
    int cm = max(c0 - 1, 0), cp = min(c1 + 1, WW - 1);
    float sy0 = (r0 == 0) ? 1.0f : 0.5f;
    float sy1 = (r1 == HH - 1) ? 1.0f : 0.5f;
    float sx0 = (c0 == 0) ? 1.0f : 0.5f;
    float sx1 = (c1 == WW - 1) ? 1.0f : 0.5f;
    const float* fr0 = f + (r0 << 8);
    const float* fr1 = f + (r1 << 8);
    const float* frm = f + (rm << 8);
    const float* frp = f + (rp << 8);
    float f00 = fr0[c0], f01 = fr0[c1];
    float f10 = fr1[c0], f11 = fr1[c1];
    float f0m = fr0[cm], f0p = fr0[cp];
    float f1m = fr1[cm], f1p = fr1[cp];
    float fm0 = frm[c0], fm1 = frm[c1];
    float fp0 = frp[c0], fp1 = frp[c1];
    float gy00 = sy0 * (f10 - fm0), gy01 = sy0 * (f11 - fm1);
    float gy10 = sy1 * (fp0 - f00), gy11 = sy1 * (fp1 - f01);
    float gx00 = sx0 * (f01 - f0m), gx01 = sx1 * (f0p - f00);
    float gx10 = sx0 * (f11 - f1m), gx11 = sx1 * (f1p - f10);
    float u = 1.0f - wy, v = 1.0f - wx;
    by = gy00 * u * v + gy01 * u * wx + gy10 * wy * v + gy11 * wy * wx;
    bx = gx00 * u * v + gx01 * u * wx + gx10 * wy * v + gx11 * wy * wx;
}

__global__ __launch_bounds__(64, 1) void evolve_direct_kernel(
        const float* __restrict__ pred,
        const float* __restrict__ nodes_in,
        float* __restrict__ nodes_out,
        int* __restrict__ counter) {
    const int b = blockIdx.x;
    const int l = threadIdx.x;
    if (b == 0 && l == 0)
        __hip_atomic_store(counter, 0, __ATOMIC_RELAXED, __HIP_MEMORY_SCOPE_AGENT);
    const float* f = pred + b * HH * WW;
    const int pl = (l + 63) & 63;
    const int nl = (l + 1) & 63;
    float4 nd = ((const float4*)nodes_in)[b * 64 + l];
    float y0n = nd.x, x0n = nd.y, y1n = nd.z, x1n = nd.w;
    for (int s = 0; s < NSTEPS_K; ++s) {
        float by0, bx0, by1, bx1;
        sample_grad_direct(f, y0n, x0n, by0, bx0);
        sample_grad_direct(f, y1n, x1n, by1, bx1);
        float pya = __shfl(y0n, pl), pxa = __shfl(x0n, pl);
        float pyb = __shfl(y1n, pl), pxb = __shfl(x1n, pl);
        float nya = __shfl(y0n, nl), nxa = __shfl(x0n, nl);
        float nyb = __shfl(y1n, nl), nxb = __shfl(x1n, nl);
        float d2ya = (y1n + pyb) - 2.0f * y0n;
        float d2xa = (x1n + pxb) - 2.0f * x0n;
        float d2yb = (nya + y0n) - 2.0f * y1n;
        float d2xb = (nxa + x0n) - 2.0f * x1n;
        float d2pyb = (y0n + pya) - 2.0f * pyb;
        float d2pxb = (x0n + pxa) - 2.0f * pxb;
        float d2nya = (nyb + y1n) - 2.0f * nya;
        float d2nxa = (nxb + x1n) - 2.0f * nxa;
        float d4ya = (d2yb + d2pyb) - 2.0f * d2ya;
        float d4xa = (d2xb + d2pxb) - 2.0f * d2xa;
        float d4yb = (d2nya + d2ya) - 2.0f * d2yb;
        float d4xb = (d2nxa + d2xa) - 2.0f * d2xb;
        y0n = y0n + 0.1f * ((0.01f * d2ya - 0.01f * d4ya) + (-10.0f * by0));
        x0n = x0n + 0.1f * ((0.01f * d2xa - 0.01f * d4xa) + (-10.0f * bx0));
        y1n = y1n + 0.1f * ((0.01f * d2yb - 0.01f * d4yb) + (-10.0f * by1));
        x1n = x1n + 0.1f * ((0.01f * d2xb - 0.01f * d4xb) + (-10.0f * bx1));
        y0n = fminf(fmaxf(y0n, 0.0f), 255.0f);
        x0n = fminf(fmaxf(x0n, 0.0f), 255.0f);
        y1n = fminf(fmaxf(y1n, 0.0f), 255.0f);
        x1n = fminf(fmaxf(x1n, 0.0f), 255.0f);
    }
    float4 o4; o4.x = y0n; o4.y = x0n; o4.z = y1n; o4.w = x1n;
    ((float4*)nodes_out)[b * 64 + l] = o4;
}

#define RBLK ((HH * WW) / 256)
#define NPART (NB * RBLK)

__global__ void render_kernel(const float* __restrict__ pred,
                              const float* __restrict__ nodes,
                              float* __restrict__ partials,
                              int* __restrict__ counter,
                              float* __restrict__ out) {
    const int b = blockIdx.y;
    const int chunk = blockIdx.x;
    const int tid = threadIdx.x;
    __shared__ float p0y[NN], p0x[NN], sdy[NN], sdx[NN], sidd[NN];
    if (tid < NN) {
        float ay = nodes[(b * NN + tid) * 2 + 0];
        float ax = nodes[(b * NN + tid) * 2 + 1];
        int j = (tid + 1) & (NN - 1);
        float cy = nodes[(b * NN + j) * 2 + 0];
        float cx = nodes[(b * NN + j) * 2 + 1];
        float ddy = cy - ay, ddx = cx - ax;
        p0y[tid] = ay; p0x[tid] = ax;
        sdy[tid] = ddy; sdx[tid] = ddx;
        sidd[tid] = 1.0f / (ddy * ddy + ddx * ddx + 1e-8f);
    }
    __syncthreads();
    const int pix = chunk * 256 + tid;
    const float qy = (float)(pix >> 8);
    const float qx = (float)(pix & (WW - 1));
    float minr2 = 1e30f;
#pragma unroll 8
    for (int s = 0; s < NN; ++s) {
        float qpy = qy - p0y[s];
        float qpx = qx - p0x[s];
        float t = (qpy * sdy[s] + qpx * sdx[s]) * sidd[s];
        t = fminf(fmaxf(t, 0.0f), 1.0f);
        float ry = qpy - t * sdy[s];
        float rx = qpx - t * sdx[s];
        minr2 = fminf(minr2, ry * ry + rx * rx);
    }
    float dist = fminf(sqrtf(minr2 + 1e-12f), 15.0f);
    float e = pred[b * HH * WW + pix] - dist;
    float se = e * e;
    for (int off = 32; off > 0; off >>= 1) se += __shfl_down(se, off);
    __shared__ float red[4];
    if ((tid & 63) == 0) red[tid >> 6] = se;
    __syncthreads();
    __shared__ int lastBlk;
    if (tid == 0) {
        float p = (red[0] + red[1]) + (red[2] + red[3]);
        __hip_atomic_store(&partials[b * RBLK + chunk], p, __ATOMIC_RELEASE, __HIP_MEMORY_SCOPE_AGENT);
        int t = __hip_atomic_fetch_add(counter, 1, __ATOMIC_ACQ_REL, __HIP_MEMORY_SCOPE_AGENT);
        lastBlk = (t == NPART - 1);
    }
    __syncthreads();
    if (lastBlk) {
        float v = __hip_atomic_load(&partials[tid], __ATOMIC_RELAXED, __HIP_MEMORY_SCOPE_AGENT)
                + __hip_atomic_load(&partials[tid + 256], __ATOMIC_RELAXED, __HIP_MEMORY_SCOPE_AGENT);
        for (int off = 32; off > 0; off >>= 1) v += __shfl_down(v, off);
        __shared__ float red2[4];
        if ((tid & 63) == 0) red2[tid >> 6] = v;
        __syncthreads();
        if (tid == 0)
            out[0] = ((red2[0] + red2[1]) + (red2[2] + red2[3])) * (1.0f / (float)(NB * HH * WW));
    }
}

extern "C" void kernel_launch(void* const* d_in, const int* in_sizes, int n_in,
                              void* d_out, int out_size, void* d_ws, size_t ws_size,
                              hipStream_t stream) {
    const float* pred = (const float*)d_in[0];    // (B,1,H,W) f32
    const float* nodes = (const float*)d_in[1];   // (B,N,2) f32
    float* ws = (float*)d_ws;

    if (ws_size >= WS_NEEDED_BYTES) {
        fused_kernel<<<dim3(NBLK), dim3(1024), 0, stream>>>(pred, nodes, ws, (float*)d_out);
    } else {
        // fallback: 2-kernel path (no gradient field buffer)
        float* partials = ws;                  // 512 f
        float* fnodes = ws + 512;              // 512 f
        int* counter = (int*)(ws + 1024);
        evolve_direct_kernel<<<dim3(NB), dim3(64), 0, stream>>>(pred, nodes, fnodes, counter);
        render_kernel<<<dim3(RBLK, NB), dim3(256), 0, stream>>>(pred, fnodes, partials,
                                                                counter, (float*)d_out);
    }
}

// Round 13
// 48.369 us; speedup vs baseline: 6.3596x; 1.7565x over previous
//
#include <hip/hip_runtime.h>

// Problem constants (match reference)
#define HH 256
#define WW 256
#define NB 2
#define NN 128
#define NSTEPS_K 50
#define NBLK 256                 // one block per CU -> co-residency guaranteed
#define MAGIC_G 0x11C0FFEE
#define MAGIC_E 0x22C0FFEE
#define MAGIC_R 0x33C0FFEE
#define SPIN_G 200000
#define SPIN_E 60000
#define SPIN_R 60000

// ws float-offsets. ALL cross-block traffic goes through MALL-coherent relaxed
// atomics -> zero buffer_wbl2 / buffer_inv inside the kernel (R12 lesson: 256
// release stores = 256 L2-writeback walks = the 23us regression).
#define WS_PART   0        // 256 floats  (per-block partials)
#define WS_GFLG   256      // 256 ints    (grad-done per block)
#define WS_RFLG   512      // 256 ints    (render-done per block)
#define WS_EREP   1024     // 16 slots * 64-int stride (evolve-done, 8 replicas/batch)
#define WS_FNODE  2048     // 512 floats = 256 u64 (final nodes)
#define WS_FIELD  4096     // NB*H*W float2 (1MB), 8B-aligned
#define WS_NEEDED_BYTES ((WS_FIELD + (size_t)NB * HH * WW * 2) * 4)

static __device__ __forceinline__ int ld_i(int* p) {
    return __hip_atomic_load(p, __ATOMIC_RELAXED, __HIP_MEMORY_SCOPE_AGENT);
}
static __device__ __forceinline__ void st_i(int* p, int v) {
    __hip_atomic_store(p, v, __ATOMIC_RELAXED, __HIP_MEMORY_SCOPE_AGENT);
}
static __device__ __forceinline__ unsigned long long ld_u64(unsigned long long* p) {
    return __hip_atomic_load(p, __ATOMIC_RELAXED, __HIP_MEMORY_SCOPE_AGENT);
}
static __device__ __forceinline__ void st_u64(unsigned long long* p, unsigned long long v) {
    __hip_atomic_store(p, v, __ATOMIC_RELAXED, __HIP_MEMORY_SCOPE_AGENT);
}
static __device__ __forceinline__ float ld_f(float* p) {
    return __hip_atomic_load(p, __ATOMIC_RELAXED, __HIP_MEMORY_SCOPE_AGENT);
}
static __device__ __forceinline__ void st_f(float* p, float v) {
    __hip_atomic_store(p, v, __ATOMIC_RELAXED, __HIP_MEMORY_SCOPE_AGENT);
}
union F2U { float2 f2; unsigned long long u; };

__global__ __launch_bounds__(1024) void fused2_kernel(
        const float* __restrict__ pred,
        const float* __restrict__ nodes_in,
        float* __restrict__ ws,
        float* __restrict__ out) {
    float* partials = ws + WS_PART;
    int*   g_flags  = (int*)(ws + WS_GFLG);
    int*   r_flags  = (int*)(ws + WS_RFLG);
    int*   e_rep    = (int*)(ws + WS_EREP);
    unsigned long long* fnodes_u = (unsigned long long*)(ws + WS_FNODE);
    unsigned long long* field_u  = (unsigned long long*)(ws + WS_FIELD);
    const float2*       field_f2 = (const float2*)(ws + WS_FIELD);

    const int blk = blockIdx.x;     // 0..255
    const int tid = threadIdx.x;    // 0..1023
    const int myBatch = blk >> 7;   // pixel batch this block renders

    // ========== Phase 1: gradient field via MALL atomics (512 cells/block) ===
    if (tid < 512) {
        int idx = blk * 512 + tid;          // 0 .. 131071
        int b = idx >> 16, p = idx & 0xFFFF;
        int i = p >> 8, j = p & (WW - 1);
        const float* f = pred + (b << 16);
        int iu = max(i - 1, 0), id = min(i + 1, HH - 1);
        int jl = max(j - 1, 0), jr = min(j + 1, WW - 1);
        float sy = (i == 0 || i == HH - 1) ? 1.0f : 0.5f;
        float sx = (j == 0 || j == WW - 1) ? 1.0f : 0.5f;
        F2U cv;
        cv.f2 = make_float2(sy * (f[(id << 8) + j] - f[(iu << 8) + j]),
                            sx * (f[(i << 8) + jr] - f[(i << 8) + jl]));
        st_u64(&field_u[idx], cv.u);        // -> MALL, no dirty L2 line
    }
    __syncthreads();                        // compiler drains vmcnt pre-barrier
    if (tid == 0) st_i(&g_flags[blk], MAGIC_G);

    // ========== Phase 2: evolve (blocks 0..NB-1) ==============================
    if (blk < NB) {
        const int b = blk;
        if (tid < 64) {   // wave0 polls the 128 producer flags of ITS batch
            int f0 = b * 128 + tid * 2;
            for (int it = 0; it < SPIN_G; ++it) {
                bool ok = (ld_i(&g_flags[f0]) == MAGIC_G) &&
                          (ld_i(&g_flags[f0 + 1]) == MAGIC_G);
                if (__all(ok)) break;
                __builtin_amdgcn_s_sleep(2);
            }
        }
        __syncthreads();

        const float2* gb = field_f2 + (b << 16);
        // warm: normal loads, L2 started clean (dispatch acquire) -> fresh MALL
        float acc = 0.0f;
        #pragma unroll
        for (int k = 0; k < 8; ++k) acc += gb[((k << 10) + tid) << 3].x;
        asm volatile("" :: "v"(acc));
        __syncthreads();

        if (tid < 64) {
            const int l = tid;
            const int pl = (l + 63) & 63;
            const int nl = (l + 1) & 63;
            float4 nd = ((const float4*)nodes_in)[b * 64 + l];
            float y0n = nd.x, x0n = nd.y;      // node 2l
            float y1n = nd.z, x1n = nd.w;      // node 2l+1

            __builtin_amdgcn_s_setprio(1);
            for (int s = 0; s < NSTEPS_K; ++s) {
                // bilerp loads first (8 x dwordx2, warm L1/L2 hits)
                float yca = fminf(fmaxf(y0n, 0.0f), 254.999f);
                float xca = fminf(fmaxf(x0n, 0.0f), 254.999f);
                int ra = (int)yca, ca = (int)xca;
                float wya = yca - (float)ra, wxa = xca - (float)ca;
                int basea = (ra << 8) + ca;
                float2 a00 = gb[basea],       a01 = gb[basea + 1];
                float2 a10 = gb[basea + WW],  a11 = gb[basea + WW + 1];

                float ycb = fminf(fmaxf(y1n, 0.0f), 254.999f);
                float xcb = fminf(fmaxf(x1n, 0.0f), 254.999f);
                int rb = (int)ycb, cb = (int)xcb;
                float wyb = ycb - (float)rb, wxb = xcb - (float)cb;
                int baseb = (rb << 8) + cb;
                float2 b00 = gb[baseb],       b01 = gb[baseb + 1];
                float2 b10 = gb[baseb + WW],  b11 = gb[baseb + WW + 1];

                // single shuffle round: neighbor positions
                float pya = __shfl(y0n, pl), pxa = __shfl(x0n, pl);
                float pyb = __shfl(y1n, pl), pxb = __shfl(x1n, pl);
                float nya = __shfl(y0n, nl), nxa = __shfl(x0n, nl);
                float nyb = __shfl(y1n, nl), nxb = __shfl(x1n, nl);

                // d2[i] = (x[i+1] + x[i-1]) - 2 x[i]
                float d2ya = (y1n + pyb) - 2.0f * y0n;
                float d2xa = (x1n + pxb) - 2.0f * x0n;
                float d2yb = (nya + y0n) - 2.0f * y1n;
                float d2xb = (nxa + x0n) - 2.0f * x1n;
                float d2pyb = (y0n + pya) - 2.0f * pyb;
                float d2pxb = (x0n + pxa) - 2.0f * pxb;
                float d2nya = (nyb + y1n) - 2.0f * nya;
                float d2nxa = (nxb + x1n) - 2.0f * nxa;

                // d4[i] = (d2[i+1] + d2[i-1]) - 2 d2[i]
                float d4ya = (d2yb + d2pyb) - 2.0f * d2ya;
                float d4xa = (d2xb + d2pxb) - 2.0f * d2xa;
                float d4yb = (d2nya + d2ya) - 2.0f * d2yb;
                float d4xb = (d2nxa + d2xa) - 2.0f * d2xb;

                // bilerp (reference term order)
                float ua = 1.0f - wya, va = 1.0f - wxa;
                float bya = a00.x * ua * va + a01.x * ua * wxa + a10.x * wya * va + a11.x * wya * wxa;
                float bxa = a00.y * ua * va + a01.y * ua * wxa + a10.y * wya * va + a11.y * wya * wxa;
                float ub = 1.0f - wyb, vb = 1.0f - wxb;
                float byb = b00.x * ub * vb + b01.x * ub * wxb + b10.x * wyb * vb + b11.x * wyb * wxb;
                float bxb = b00.y * ub * vb + b01.y * ub * wxb + b10.y * wyb * vb + b11.y * wyb * wxb;

                // x += STEPSZ*(ALPHA*d2 - BETA*d4 + ext); clip [0,255]
                y0n = y0n + 0.1f * ((0.01f * d2ya - 0.01f * d4ya) + (-10.0f * bya));
                x0n = x0n + 0.1f * ((0.01f * d2xa - 0.01f * d4xa) + (-10.0f * bxa));
                y1n = y1n + 0.1f * ((0.01f * d2yb - 0.01f * d4yb) + (-10.0f * byb));
                x1n = x1n + 0.1f * ((0.01f * d2xb - 0.01f * d4xb) + (-10.0f * bxb));
                y0n = fminf(fmaxf(y0n, 0.0f), 255.0f);
                x0n = fminf(fmaxf(x0n, 0.0f), 255.0f);
                y1n = fminf(fmaxf(y1n, 0.0f), 255.0f);
                x1n = fminf(fmaxf(x1n, 0.0f), 255.0f);
            }
            __builtin_amdgcn_s_setprio(0);

            // publish nodes via MALL atomics; vmcnt(0) orders flag AFTER data
            F2U c0, c1;
            c0.f2 = make_float2(y0n, x0n);
            c1.f2 = make_float2(y1n, x1n);
            st_u64(&fnodes_u[b * 128 + 2 * l], c0.u);
            st_u64(&fnodes_u[b * 128 + 2 * l + 1], c1.u);
            asm volatile("s_waitcnt vmcnt(0)" ::: "memory");
            if (l == 0) {
                #pragma unroll
                for (int k = 0; k < 8; ++k) st_i(&e_rep[(b * 8 + k) * 64], MAGIC_E);
            }
        }
        __syncthreads();
    }

    // ========== e-wait: only myBatch's flag, replicated lines, long sleeps ====
    if (tid == 0) {
        int* rep = &e_rep[(myBatch * 8 + (blk & 7)) * 64];
        for (int it = 0; it < SPIN_E; ++it) {
            if (ld_i(rep) == MAGIC_E) break;
            __builtin_amdgcn_s_sleep(32);
        }
    }
    __syncthreads();

    // ========== Phase 3: render (512 px/block, batch = myBatch) ===============
    __shared__ float nny[NN], nnx[NN];
    __shared__ float p0y[NN], p0x[NN], sdy[NN], sdx[NN], sidd[NN];
    if (tid < NN) {   // stage nodes via MALL atomic loads (no acquire needed)
        F2U cv; cv.u = ld_u64(&fnodes_u[myBatch * 128 + tid]);
        nny[tid] = cv.f2.x; nnx[tid] = cv.f2.y;
    }
    __syncthreads();
    if (tid < NN) {
        float ay = nny[tid], ax = nnx[tid];
        int j = (tid + 1) & (NN - 1);
        float cy = nny[j], cx = nnx[j];
        float ddy = cy - ay, ddx = cx - ax;
        p0y[tid] = ay; p0x[tid] = ax;
        sdy[tid] = ddy; sdx[tid] = ddx;
        sidd[tid] = 1.0f / (ddy * ddy + ddx * ddx + 1e-8f);
    }
    __syncthreads();

    float se = 0.0f;
    if (tid < 512) {
        int pixin = (blk & 127) * 512 + tid;    // 0 .. 65535 within batch
        float qy = (float)(pixin >> 8);
        float qx = (float)(pixin & (WW - 1));
        float minr2 = 1e30f;
        #pragma unroll 8
        for (int s = 0; s < NN; ++s) {
            float qpy = qy - p0y[s];
            float qpx = qx - p0x[s];
            float t = (qpy * sdy[s] + qpx * sdx[s]) * sidd[s];
            t = fminf(fmaxf(t, 0.0f), 1.0f);
            float ry = qpy - t * sdy[s];
            float rx = qpx - t * sdx[s];
            minr2 = fminf(minr2, ry * ry + rx * rx);
        }
        float dist = fminf(sqrtf(minr2 + 1e-12f), 15.0f);
        float e = pred[(myBatch << 16) + pixin] - dist;
        se = e * e;
    }
    for (int off = 32; off > 0; off >>= 1) se += __shfl_down(se, off);
    __shared__ float red[16];
    if ((tid & 63) == 0) red[tid >> 6] = se;   // waves 8..15 write 0
    __syncthreads();
    if (tid == 0) {
        float p = 0.0f;
        #pragma unroll
        for (int w = 0; w < 8; ++w) p += red[w];
        st_f(&partials[blk], p);
        asm volatile("s_waitcnt vmcnt(0)" ::: "memory");   // partial before flag
        st_i(&r_flags[blk], MAGIC_R);
    }

    // ========== Phase 4: finalize + flag reset (block 0) ======================
    if (blk == 0 && tid < 64) {
        for (int it = 0; it < SPIN_R; ++it) {
            bool ok = (ld_i(&r_flags[tid*4+0]) == MAGIC_R) &&
                      (ld_i(&r_flags[tid*4+1]) == MAGIC_R) &&
                      (ld_i(&r_flags[tid*4+2]) == MAGIC_R) &&
                      (ld_i(&r_flags[tid*4+3]) == MAGIC_R);
            if (__all(ok)) break;
            __builtin_amdgcn_s_sleep(8);
        }
        float s = 0.0f;
        #pragma unroll
        for (int k = 0; k < 4; ++k)   // fixed order -> deterministic
            s += ld_f(&partials[tid + (k << 6)]);
        for (int off = 32; off > 0; off >>= 1) s += __shfl_down(s, off);
        if (tid == 0) out[0] = s * (1.0f / (float)(NB * HH * WW));
        // reset flags (relaxed MALL stores; everyone is past their last read)
        #pragma unroll
        for (int k = 0; k < 4; ++k) { st_i(&g_flags[tid*4+k], 0); st_i(&r_flags[tid*4+k], 0); }
        if (tid < 16) st_i(&e_rep[tid * 64], 0);
    }
}

// ---------------- fallback (ws too small): 2-kernel path ---------------------
__device__ __forceinline__ void sample_grad_direct(const float* __restrict__ f,
                                                   float y, float x,
                                                   float& by, float& bx) {
    float yc = fminf(fmaxf(y, 0.0f), 254.999f);
    float xc = fminf(fmaxf(x, 0.0f), 254.999f);
    int r0 = (int)yc, c0 = (int)xc;
    int r1 = r0 + 1, c1 = c0 + 1;
    float wy = yc - (float)r0, wx = xc - (float)c0;
    int rm = max(r0 - 1, 0), rp = min(r1 + 1, HH - 1);
    int cm = max(c0 - 1, 0), cp = min(c1 + 1, WW - 1);
    float sy0 = (r0 == 0) ? 1.0f : 0.5f;
    float sy1 = (r1 == HH - 1) ? 1.0f : 0.5f;
    float sx0 = (c0 == 0) ? 1.0f : 0.5f;
    float sx1 = (c1 == WW - 1) ? 1.0f : 0.5f;
    const float* fr0 = f + (r0 << 8);
    const float* fr1 = f + (r1 << 8);
    const float* frm = f + (rm << 8);
    const float* frp = f + (rp << 8);
    float f00 = fr0[c0], f01 = fr0[c1];
    float f10 = fr1[c0], f11 = fr1[c1];
    float f0m = fr0[cm], f0p = fr0[cp];
    float f1m = fr1[cm], f1p = fr1[cp];
    float fm0 = frm[c0], fm1 = frm[c1];
    float fp0 = frp[c0], fp1 = frp[c1];
    float gy00 = sy0 * (f10 - fm0), gy01 = sy0 * (f11 - fm1);
    float gy10 = sy1 * (fp0 - f00), gy11 = sy1 * (fp1 - f01);
    float gx00 = sx0 * (f01 - f0m), gx01 = sx1 * (f0p - f00);
    float gx10 = sx0 * (f11 - f1m), gx11 = sx1 * (f1p - f10);
    float u = 1.0f - wy, v = 1.0f - wx;
    by = gy00 * u * v + gy01 * u * wx + gy10 * wy * v + gy11 * wy * wx;
    bx = gx00 * u * v + gx01 * u * wx + gx10 * wy * v + gx11 * wy * wx;
}

__global__ __launch_bounds__(64, 1) void evolve_direct_kernel(
        const float* __restrict__ pred,
        const float* __restrict__ nodes_in,
        float* __restrict__ nodes_out,
        int* __restrict__ counter) {
    const int b = blockIdx.x;
    const int l = threadIdx.x;
    if (b == 0 && l == 0)
        __hip_atomic_store(counter, 0, __ATOMIC_RELAXED, __HIP_MEMORY_SCOPE_AGENT);
    const float* f = pred + b * HH * WW;
    const int pl = (l + 63) & 63;
    const int nl = (l + 1) & 63;
    float4 nd = ((const float4*)nodes_in)[b * 64 + l];
    float y0n = nd.x, x0n = nd.y, y1n = nd.z, x1n = nd.w;
    for (int s = 0; s < NSTEPS_K; ++s) {
        float by0, bx0, by1, bx1;
        sample_grad_direct(f, y0n, x0n, by0, bx0);
        sample_grad_direct(f, y1n, x1n, by1, bx1);
        float pya = __shfl(y0n, pl), pxa = __shfl(x0n, pl);
        float pyb = __shfl(y1n, pl), pxb = __shfl(x1n, pl);
        float nya = __shfl(y0n, nl), nxa = __shfl(x0n, nl);
        float nyb = __shfl(y1n, nl), nxb = __shfl(x1n, nl);
        float d2ya = (y1n + pyb) - 2.0f * y0n;
        float d2xa = (x1n + pxb) - 2.0f * x0n;
        float d2yb = (nya + y0n) - 2.0f * y1n;
        float d2xb = (nxa + x0n) - 2.0f * x1n;
        float d2pyb = (y0n + pya) - 2.0f * pyb;
        float d2pxb = (x0n + pxa) - 2.0f * pxb;
        float d2nya = (nyb + y1n) - 2.0f * nya;
        float d2nxa = (nxb + x1n) - 2.0f * nxa;
        float d4ya = (d2yb + d2pyb) - 2.0f * d2ya;
        float d4xa = (d2xb + d2pxb) - 2.0f * d2xa;
        float d4yb = (d2nya + d2ya) - 2.0f * d2yb;
        float d4xb = (d2nxa + d2xa) - 2.0f * d2xb;
        y0n = y0n + 0.1f * ((0.01f * d2ya - 0.01f * d4ya) + (-10.0f * by0));
        x0n = x0n + 0.1f * ((0.01f * d2xa - 0.01f * d4xa) + (-10.0f * bx0));
        y1n = y1n + 0.1f * ((0.01f * d2yb - 0.01f * d4yb) + (-10.0f * by1));
        x1n = x1n + 0.1f * ((0.01f * d2xb - 0.01f * d4xb) + (-10.0f * bx1));
        y0n = fminf(fmaxf(y0n, 0.0f), 255.0f);
        x0n = fminf(fmaxf(x0n, 0.0f), 255.0f);
        y1n = fminf(fmaxf(y1n, 0.0f), 255.0f);
        x1n = fminf(fmaxf(x1n, 0.0f), 255.0f);
    }
    float4 o4; o4.x = y0n; o4.y = x0n; o4.z = y1n; o4.w = x1n;
    ((float4*)nodes_out)[b * 64 + l] = o4;
}

#define RBLK ((HH * WW) / 256)
#define NPART (NB * RBLK)

__global__ void render_kernel(const float* __restrict__ pred,
                              const float* __restrict__ nodes,
                              float* __restrict__ partials,
                              int* __restrict__ counter,
                              float* __restrict__ out) {
    const int b = blockIdx.y;
    const int chunk = blockIdx.x;
    const int tid = threadIdx.x;
    __shared__ float p0y[NN], p0x[NN], sdy[NN], sdx[NN], sidd[NN];
    if (tid < NN) {
        float ay = nodes[(b * NN + tid) * 2 + 0];
        float ax = nodes[(b * NN + tid) * 2 + 1];
        int j = (tid + 1) & (NN - 1);
        float cy = nodes[(b * NN + j) * 2 + 0];
        float cx = nodes[(b * NN + j) * 2 + 1];
        float ddy = cy - ay, ddx = cx - ax;
        p0y[tid] = ay; p0x[tid] = ax;
        sdy[tid] = ddy; sdx[tid] = ddx;
        sidd[tid] = 1.0f / (ddy * ddy + ddx * ddx + 1e-8f);
    }
    __syncthreads();
    const int pix = chunk * 256 + tid;
    const float qy = (float)(pix >> 8);
    const float qx = (float)(pix & (WW - 1));
    float minr2 = 1e30f;
#pragma unroll 8
    for (int s = 0; s < NN; ++s) {
        float qpy = qy - p0y[s];
        float qpx = qx - p0x[s];
        float t = (qpy * sdy[s] + qpx * sdx[s]) * sidd[s];
        t = fminf(fmaxf(t, 0.0f), 1.0f);
        float ry = qpy - t * sdy[s];
        float rx = qpx - t * sdx[s];
        minr2 = fminf(minr2, ry * ry + rx * rx);
    }
    float dist = fminf(sqrtf(minr2 + 1e-12f), 15.0f);
    float e = pred[b * HH * WW + pix] - dist;
    float se = e * e;
    for (int off = 32; off > 0; off >>= 1) se += __shfl_down(se, off);
    __shared__ float red[4];
    if ((tid & 63) == 0) red[tid >> 6] = se;
    __syncthreads();
    __shared__ int lastBlk;
    if (tid == 0) {
        float p = (red[0] + red[1]) + (red[2] + red[3]);
        __hip_atomic_store(&partials[b * RBLK + chunk], p, __ATOMIC_RELEASE, __HIP_MEMORY_SCOPE_AGENT);
        int t = __hip_atomic_fetch_add(counter, 1, __ATOMIC_ACQ_REL, __HIP_MEMORY_SCOPE_AGENT);
        lastBlk = (t == NPART - 1);
    }
    __syncthreads();
    if (lastBlk) {
        float v = __hip_atomic_load(&partials[tid], __ATOMIC_RELAXED, __HIP_MEMORY_SCOPE_AGENT)
                + __hip_atomic_load(&partials[tid + 256], __ATOMIC_RELAXED, __HIP_MEMORY_SCOPE_AGENT);
        for (int off = 32; off > 0; off >>= 1) v += __shfl_down(v, off);
        __shared__ float red2[4];
        if ((tid & 63) == 0) red2[tid >> 6] = v;
        __syncthreads();
        if (tid == 0)
            out[0] = ((red2[0] + red2[1]) + (red2[2] + red2[3])) * (1.0f / (float)(NB * HH * WW));
    }
}

extern "C" void kernel_launch(void* const* d_in, const int* in_sizes, int n_in,
                              void* d_out, int out_size, void* d_ws, size_t ws_size,
                              hipStream_t stream) {
    const float* pred = (const float*)d_in[0];    // (B,1,H,W) f32
    const float* nodes = (const float*)d_in[1];   // (B,N,2) f32
    float* ws = (float*)d_ws;

    if (ws_size >= WS_NEEDED_BYTES) {
        fused2_kernel<<<dim3(NBLK), dim3(1024), 0, stream>>>(pred, nodes, ws, (float*)d_out);
    } else {
        float* partials = ws;                  // 512 f
        float* fnodes = ws + 512;              // 512 f
        int* counter = (int*)(ws + 1024);
        evolve_direct_kernel<<<dim3(NB), dim3(64), 0, stream>>>(pred, nodes, fnodes, counter);
        render_kernel<<<dim3(RBLK, NB), dim3(256), 0, stream>>>(pred, fnodes, partials,
                                                                counter, (float*)d_out);
    }
}

// Round 14
// 47.093 us; speedup vs baseline: 6.5319x; 1.0271x over previous
//
#include <hip/hip_runtime.h>

// Problem constants (match reference)
#define HH 256
#define WW 256
#define NB 2
#define NN 128
#define NSTEPS_K 50
#define NBLK 256                 // one block per CU -> co-residency guaranteed
#define MAGIC_G 0x11C0FFEE
#define MAGIC_E 0x22C0FFEE
#define MAGIC_R 0x33C0FFEE
#define SPIN_G 400000
#define SPIN_E 120000
#define SPIN_R 120000

// ws float-offsets. ALL cross-block traffic goes through MALL-coherent relaxed
// atomics -> zero buffer_wbl2 / buffer_inv inside the kernel (R11/R12 lessons:
// per-iteration acquire = invalidate storm; per-block release = writeback storm).
#define WS_PART   0        // 256 floats  (per-block partials)
#define WS_GFLG   256      // 256 ints    (grad-done per block)
#define WS_RFLG   512      // 256 ints    (render-done per block)
#define WS_EREP   1024     // 16 slots * 64-int stride (evolve-done, 8 replicas/batch)
#define WS_FNODE  2048     // 512 floats = 256 u64 (final nodes)
#define WS_FIELD  4096     // NB*H*W float2 (1MB), 8B-aligned
#define WS_NEEDED_BYTES ((WS_FIELD + (size_t)NB * HH * WW * 2) * 4)

static __device__ __forceinline__ int ld_i(int* p) {
    return __hip_atomic_load(p, __ATOMIC_RELAXED, __HIP_MEMORY_SCOPE_AGENT);
}
static __device__ __forceinline__ void st_i(int* p, int v) {
    __hip_atomic_store(p, v, __ATOMIC_RELAXED, __HIP_MEMORY_SCOPE_AGENT);
}
static __device__ __forceinline__ unsigned long long ld_u64(unsigned long long* p) {
    return __hip_atomic_load(p, __ATOMIC_RELAXED, __HIP_MEMORY_SCOPE_AGENT);
}
static __device__ __forceinline__ void st_u64(unsigned long long* p, unsigned long long v) {
    __hip_atomic_store(p, v, __ATOMIC_RELAXED, __HIP_MEMORY_SCOPE_AGENT);
}
static __device__ __forceinline__ float ld_f(float* p) {
    return __hip_atomic_load(p, __ATOMIC_RELAXED, __HIP_MEMORY_SCOPE_AGENT);
}
static __device__ __forceinline__ void st_f(float* p, float v) {
    __hip_atomic_store(p, v, __ATOMIC_RELAXED, __HIP_MEMORY_SCOPE_AGENT);
}
union F2U { float2 f2; unsigned long long u; };

// 16B row-pair load at 8B alignment -> compiler emits one global_load_dwordx4
// (gfx950 global loads need only dword alignment). Components in memory order:
// r[0]=cell0.gy r[1]=cell0.gx r[2]=cell1.gy r[3]=cell1.gx  (bit-identical use).
typedef float f4v __attribute__((ext_vector_type(4)));
static __device__ __forceinline__ f4v ld_pair(const float2* p) {
    f4v r;
    __builtin_memcpy(&r, p, sizeof(f4v));
    return r;
}

__global__ __launch_bounds__(1024) void fused3_kernel(
        const float* __restrict__ pred,
        const float* __restrict__ nodes_in,
        float* __restrict__ ws,
        float* __restrict__ out) {
    float* partials = ws + WS_PART;
    int*   g_flags  = (int*)(ws + WS_GFLG);
    int*   r_flags  = (int*)(ws + WS_RFLG);
    int*   e_rep    = (int*)(ws + WS_EREP);
    unsigned long long* fnodes_u = (unsigned long long*)(ws + WS_FNODE);
    unsigned long long* field_u  = (unsigned long long*)(ws + WS_FIELD);
    const float2*       field_f2 = (const float2*)(ws + WS_FIELD);

    const int blk = blockIdx.x;     // 0..255
    const int tid = threadIdx.x;    // 0..1023
    const int myBatch = blk >> 7;   // pixel batch this block renders

    // ========== Phase 1: gradient field via MALL atomics (512 cells/block) ===
    if (tid < 512) {
        int idx = blk * 512 + tid;          // 0 .. 131071
        int b = idx >> 16, p = idx & 0xFFFF;
        int i = p >> 8, j = p & (WW - 1);
        const float* f = pred + (b << 16);
        int iu = max(i - 1, 0), id = min(i + 1, HH - 1);
        int jl = max(j - 1, 0), jr = min(j + 1, WW - 1);
        float sy = (i == 0 || i == HH - 1) ? 1.0f : 0.5f;
        float sx = (j == 0 || j == WW - 1) ? 1.0f : 0.5f;
        F2U cv;
        cv.f2 = make_float2(sy * (f[(id << 8) + j] - f[(iu << 8) + j]),
                            sx * (f[(i << 8) + jr] - f[(i << 8) + jl]));
        st_u64(&field_u[idx], cv.u);        // -> MALL, no dirty L2 line
    }
    __syncthreads();                        // drains vmcnt pre-barrier
    if (tid == 0) st_i(&g_flags[blk], MAGIC_G);

    // ========== Phase 2: evolve (blocks 0..NB-1) ==============================
    if (blk < NB) {
        const int b = blk;
        const float2* gb = field_f2 + (b << 16);

        // ---- PIPELINED poll+warm: wave w, chunk k covers cells
        // [k*8192 + w*512, +512) = exactly producer block b*128 + k*16 + w.
        // Poll that one flag, then warm the chunk's 64 cache lines (1/lane).
        // After __syncthreads(): entire field produced AND L2-resident.
        {
            const int w = tid >> 6, ln = tid & 63;
            float acc = 0.0f;
            #pragma unroll
            for (int k = 0; k < 8; ++k) {
                int* fl = &g_flags[b * 128 + k * 16 + w];
                for (int it = 0; it < SPIN_G; ++it) {
                    if (ld_i(fl) == MAGIC_G) break;
                    __builtin_amdgcn_s_sleep(1);
                }
                acc += gb[(k * 1024 + w * 64 + ln) << 3].x;  // 8B of each 64B line
            }
            asm volatile("" :: "v"(acc));    // no DCE
        }
        __syncthreads();

        if (tid < 64) {
            const int l = tid;
            const int pl = (l + 63) & 63;
            const int nl = (l + 1) & 63;
            float4 nd = ((const float4*)nodes_in)[b * 64 + l];
            float y0n = nd.x, x0n = nd.y;      // node 2l
            float y1n = nd.z, x1n = nd.w;      // node 2l+1

            __builtin_amdgcn_s_setprio(1);
            for (int s = 0; s < NSTEPS_K; ++s) {
                // 4 x dwordx4 row-pair loads (was 8 x dwordx2) -- same bytes
                float yca = fminf(fmaxf(y0n, 0.0f), 254.999f);
                float xca = fminf(fmaxf(x0n, 0.0f), 254.999f);
                int ra = (int)yca, ca = (int)xca;
                float wya = yca - (float)ra, wxa = xca - (float)ca;
                int basea = (ra << 8) + ca;
                f4v ra0 = ld_pair(&gb[basea]);        // a00.gy a00.gx a01.gy a01.gx
                f4v ra1 = ld_pair(&gb[basea + WW]);   // a10.gy a10.gx a11.gy a11.gx

                float ycb = fminf(fmaxf(y1n, 0.0f), 254.999f);
                float xcb = fminf(fmaxf(x1n, 0.0f), 254.999f);
                int rb = (int)ycb, cb = (int)xcb;
                float wyb = ycb - (float)rb, wxb = xcb - (float)cb;
                int baseb = (rb << 8) + cb;
                f4v rb0 = ld_pair(&gb[baseb]);
                f4v rb1 = ld_pair(&gb[baseb + WW]);

                // single shuffle round: neighbor positions
                float pya = __shfl(y0n, pl), pxa = __shfl(x0n, pl);
                float pyb = __shfl(y1n, pl), pxb = __shfl(x1n, pl);
                float nya = __shfl(y0n, nl), nxa = __shfl(x0n, nl);
                float nyb = __shfl(y1n, nl), nxb = __shfl(x1n, nl);

                // d2[i] = (x[i+1] + x[i-1]) - 2 x[i]
                float d2ya = (y1n + pyb) - 2.0f * y0n;
                float d2xa = (x1n + pxb) - 2.0f * x0n;
                float d2yb = (nya + y0n) - 2.0f * y1n;
                float d2xb = (nxa + x0n) - 2.0f * x1n;
                float d2pyb = (y0n + pya) - 2.0f * pyb;
                float d2pxb = (x0n + pxa) - 2.0f * pxb;
                float d2nya = (nyb + y1n) - 2.0f * nya;
                float d2nxa = (nxb + x1n) - 2.0f * nxa;

                // d4[i] = (d2[i+1] + d2[i-1]) - 2 d2[i]
                float d4ya = (d2yb + d2pyb) - 2.0f * d2ya;
                float d4xa = (d2xb + d2pxb) - 2.0f * d2xa;
                float d4yb = (d2nya + d2ya) - 2.0f * d2yb;
                float d4xb = (d2nxa + d2xa) - 2.0f * d2xb;

                // bilerp (reference term order; component mapping unchanged)
                float ua = 1.0f - wya, va = 1.0f - wxa;
                float bya = ra0[0] * ua * va + ra0[2] * ua * wxa + ra1[0] * wya * va + ra1[2] * wya * wxa;
                float bxa = ra0[1] * ua * va + ra0[3] * ua * wxa + ra1[1] * wya * va + ra1[3] * wya * wxa;
                float ub = 1.0f - wyb, vb = 1.0f - wxb;
                float byb = rb0[0] * ub * vb + rb0[2] * ub * wxb + rb1[0] * wyb * vb + rb1[2] * wyb * wxb;
                float bxb = rb0[1] * ub * vb + rb0[3] * ub * wxb + rb1[1] * wyb * vb + rb1[3] * wyb * wxb;

                // x += STEPSZ*(ALPHA*d2 - BETA*d4 + ext); clip [0,255]
                y0n = y0n + 0.1f * ((0.01f * d2ya - 0.01f * d4ya) + (-10.0f * bya));
                x0n = x0n + 0.1f * ((0.01f * d2xa - 0.01f * d4xa) + (-10.0f * bxa));
                y1n = y1n + 0.1f * ((0.01f * d2yb - 0.01f * d4yb) + (-10.0f * byb));
                x1n = x1n + 0.1f * ((0.01f * d2xb - 0.01f * d4xb) + (-10.0f * bxb));
                y0n = fminf(fmaxf(y0n, 0.0f), 255.0f);
                x0n = fminf(fmaxf(x0n, 0.0f), 255.0f);
                y1n = fminf(fmaxf(y1n, 0.0f), 255.0f);
                x1n = fminf(fmaxf(x1n, 0.0f), 255.0f);
            }
            __builtin_amdgcn_s_setprio(0);

            // publish nodes via MALL atomics; vmcnt(0) orders flag AFTER data
            F2U c0, c1;
            c0.f2 = make_float2(y0n, x0n);
            c1.f2 = make_float2(y1n, x1n);
            st_u64(&fnodes_u[b * 128 + 2 * l], c0.u);
            st_u64(&fnodes_u[b * 128 + 2 * l + 1], c1.u);
            asm volatile("s_waitcnt vmcnt(0)" ::: "memory");
            if (l == 0) {
                #pragma unroll
                for (int k = 0; k < 8; ++k) st_i(&e_rep[(b * 8 + k) * 64], MAGIC_E);
            }
        }
        __syncthreads();
    }

    // ========== e-wait: only myBatch's flag, replicated lines =================
    if (tid == 0) {
        int* rep = &e_rep[(myBatch * 8 + (blk & 7)) * 64];
        for (int it = 0; it < SPIN_E; ++it) {
            if (ld_i(rep) == MAGIC_E) break;
            __builtin_amdgcn_s_sleep(8);
        }
    }
    __syncthreads();

    // ========== Phase 3: render (512 px/block, batch = myBatch) ===============
    __shared__ float nny[NN], nnx[NN];
    __shared__ float p0y[NN], p0x[NN], sdy[NN], sdx[NN], sidd[NN];
    if (tid < NN) {   // stage nodes via MALL atomic loads (no acquire needed)
        F2U cv; cv.u = ld_u64(&fnodes_u[myBatch * 128 + tid]);
        nny[tid] = cv.f2.x; nnx[tid] = cv.f2.y;
    }
    __syncthreads();
    if (tid < NN) {
        float ay = nny[tid], ax = nnx[tid];
        int j = (tid + 1) & (NN - 1);
        float cy = nny[j], cx = nnx[j];
        float ddy = cy - ay, ddx = cx - ax;
        p0y[tid] = ay; p0x[tid] = ax;
        sdy[tid] = ddy; sdx[tid] = ddx;
        sidd[tid] = 1.0f / (ddy * ddy + ddx * ddx + 1e-8f);
    }
    __syncthreads();

    float se = 0.0f;
    if (tid < 512) {
        int pixin = (blk & 127) * 512 + tid;    // 0 .. 65535 within batch
        float qy = (float)(pixin >> 8);
        float qx = (float)(pixin & (WW - 1));
        float minr2 = 1e30f;
        #pragma unroll 8
        for (int s = 0; s < NN; ++s) {
            float qpy = qy - p0y[s];
            float qpx = qx - p0x[s];
            float t = (qpy * sdy[s] + qpx * sdx[s]) * sidd[s];
            t = fminf(fmaxf(t, 0.0f), 1.0f);
            float ry = qpy - t * sdy[s];
            float rx = qpx - t * sdx[s];
            minr2 = fminf(minr2, ry * ry + rx * rx);
        }
        float dist = fminf(sqrtf(minr2 + 1e-12f), 15.0f);
        float e = pred[(myBatch << 16) + pixin] - dist;
        se = e * e;
    }
    for (int off = 32; off > 0; off >>= 1) se += __shfl_down(se, off);
    __shared__ float red[16];
    if ((tid & 63) == 0) red[tid >> 6] = se;   // waves 8..15 write 0
    __syncthreads();
    if (tid == 0) {
        float p = 0.0f;
        #pragma unroll
        for (int w = 0; w < 8; ++w) p += red[w];
        st_f(&partials[blk], p);
        asm volatile("s_waitcnt vmcnt(0)" ::: "memory");   // partial before flag
        st_i(&r_flags[blk], MAGIC_R);
    }

    // ========== Phase 4: finalize + flag reset (block 0) ======================
    if (blk == 0 && tid < 64) {
        for (int it = 0; it < SPIN_R; ++it) {
            bool ok = (ld_i(&r_flags[tid*4+0]) == MAGIC_R) &&
                      (ld_i(&r_flags[tid*4+1]) == MAGIC_R) &&
                      (ld_i(&r_flags[tid*4+2]) == MAGIC_R) &&
                      (ld_i(&r_flags[tid*4+3]) == MAGIC_R);
            if (__all(ok)) break;
            __builtin_amdgcn_s_sleep(8);
        }
        float s = 0.0f;
        #pragma unroll
        for (int k = 0; k < 4; ++k)   // fixed order -> deterministic
            s += ld_f(&partials[tid + (k << 6)]);
        for (int off = 32; off > 0; off >>= 1) s += __shfl_down(s, off);
        if (tid == 0) out[0] = s * (1.0f / (float)(NB * HH * WW));
        // reset flags (relaxed MALL stores; everyone is past their last read)
        #pragma unroll
        for (int k = 0; k < 4; ++k) { st_i(&g_flags[tid*4+k], 0); st_i(&r_flags[tid*4+k], 0); }
        if (tid < 16) st_i(&e_rep[tid * 64], 0);
    }
}

// ---------------- fallback (ws too small): 2-kernel path ---------------------
__device__ __forceinline__ void sample_grad_direct(const float* __restrict__ f,
                                                   float y, float x,
                                                   float& by, float& bx) {
    float yc = fminf(fmaxf(y, 0.0f), 254.999f);
    float xc = fminf(fmaxf(x, 0.0f), 254.999f);
    int r0 = (int)yc, c0 = (int)xc;
    int r1 = r0 + 1, c1 = c0 + 1;
    float wy = yc - (float)r0, wx = xc - (float)c0;
    int rm = max(r0 - 1, 0), rp = min(r1 + 1, HH - 1);
    int cm = max(c0 - 1, 0), cp = min(c1 + 1, WW - 1);
    float sy0 = (r0 == 0) ? 1.0f : 0.5f;
    float sy1 = (r1 == HH - 1) ? 1.0f : 0.5f;
    float sx0 = (c0 == 0) ? 1.0f : 0.5f;
    float sx1 = (c1 == WW - 1) ? 1.0f : 0.5f;
    const float* fr0 = f + (r0 << 8);
    const float* fr1 = f + (r1 << 8);
    const float* frm = f + (rm << 8);
    const float* frp = f + (rp << 8);
    float f00 = fr0[c0], f01 = fr0[c1];
    float f10 = fr1[c0], f11 = fr1[c1];
    float f0m = fr0[cm], f0p = fr0[cp];
    float f1m = fr1[cm], f1p = fr1[cp];
    float fm0 = frm[c0], fm1 = frm[c1];
    float fp0 = frp[c0], fp1 = frp[c1];
    float gy00 = sy0 * (f10 - fm0), gy01 = sy0 * (f11 - fm1);
    float gy10 = sy1 * (fp0 - f00), gy11 = sy1 * (fp1 - f01);
    float gx00 = sx0 * (f01 - f0m), gx01 = sx1 * (f0p - f00);
    float gx10 = sx0 * (f11 - f1m), gx11 = sx1 * (f1p - f10);
    float u = 1.0f - wy, v = 1.0f - wx;
    by = gy00 * u * v + gy01 * u * wx + gy10 * wy * v + gy11 * wy * wx;
    bx = gx00 * u * v + gx01 * u * wx + gx10 * wy * v + gx11 * wy * wx;
}

__global__ __launch_bounds__(64, 1) void evolve_direct_kernel(
        const float* __restrict__ pred,
        const float* __restrict__ nodes_in,
        float* __restrict__ nodes_out,
        int* __restrict__ counter) {
    const int b = blockIdx.x;
    const int l = threadIdx.x;
    if (b == 0 && l == 0)
        __hip_atomic_store(counter, 0, __ATOMIC_RELAXED, __HIP_MEMORY_SCOPE_AGENT);
    const float* f = pred + b * HH * WW;
    const int pl = (l + 63) & 63;
    const int nl = (l + 1) & 63;
    float4 nd = ((const float4*)nodes_in)[b * 64 + l];
    float y0n = nd.x, x0n = nd.y, y1n = nd.z, x1n = nd.w;
    for (int s = 0; s < NSTEPS_K; ++s) {
        float by0, bx0, by1, bx1;
        sample_grad_direct(f, y0n, x0n, by0, bx0);
        sample_grad_direct(f, y1n, x1n, by1, bx1);
        float pya = __shfl(y0n, pl), pxa = __shfl(x0n, pl);
        float pyb = __shfl(y1n, pl), pxb = __shfl(x1n, pl);
        float nya = __shfl(y0n, nl), nxa = __shfl(x0n, nl);
        float nyb = __shfl(y1n, nl), nxb = __shfl(x1n, nl);
        float d2ya = (y1n + pyb) - 2.0f * y0n;
        float d2xa = (x1n + pxb) - 2.0f * x0n;
        float d2yb = (nya + y0n) - 2.0f * y1n;
        float d2xb = (nxa + x0n) - 2.0f * x1n;
        float d2pyb = (y0n + pya) - 2.0f * pyb;
        float d2pxb = (x0n + pxa) - 2.0f * pxb;
        float d2nya = (nyb + y1n) - 2.0f * nya;
        float d2nxa = (nxb + x1n) - 2.0f * nxa;
        float d4ya = (d2yb + d2pyb) - 2.0f * d2ya;
        float d4xa = (d2xb + d2pxb) - 2.0f * d2xa;
        float d4yb = (d2nya + d2ya) - 2.0f * d2yb;
        float d4xb = (d2nxa + d2xa) - 2.0f * d2xb;
        y0n = y0n + 0.1f * ((0.01f * d2ya - 0.01f * d4ya) + (-10.0f * by0));
        x0n = x0n + 0.1f * ((0.01f * d2xa - 0.01f * d4xa) + (-10.0f * bx0));
        y1n = y1n + 0.1f * ((0.01f * d2yb - 0.01f * d4yb) + (-10.0f * by1));
        x1n = x1n + 0.1f * ((0.01f * d2xb - 0.01f * d4xb) + (-10.0f * bx1));
        y0n = fminf(fmaxf(y0n, 0.0f), 255.0f);
        x0n = fminf(fmaxf(x0n, 0.0f), 255.0f);
        y1n = fminf(fmaxf(y1n, 0.0f), 255.0f);
        x1n = fminf(fmaxf(x1n, 0.0f), 255.0f);
    }
    float4 o4; o4.x = y0n; o4.y = x0n; o4.z = y1n; o4.w = x1n;
    ((float4*)nodes_out)[b * 64 + l] = o4;
}

#define RBLK ((HH * WW) / 256)
#define NPART (NB * RBLK)

__global__ void render_kernel(const float* __restrict__ pred,
                              const float* __restrict__ nodes,
                              float* __restrict__ partials,
                              int* __restrict__ counter,
                              float* __restrict__ out) {
    const int b = blockIdx.y;
    const int chunk = blockIdx.x;
    const int tid = threadIdx.x;
    __shared__ float p0y[NN], p0x[NN], sdy[NN], sdx[NN], sidd[NN];
    if (tid < NN) {
        float ay = nodes[(b * NN + tid) * 2 + 0];
        float ax = nodes[(b * NN + tid) * 2 + 1];
        int j = (tid + 1) & (NN - 1);
        float cy = nodes[(b * NN + j) * 2 + 0];
        float cx = nodes[(b * NN + j) * 2 + 1];
        float ddy = cy - ay, ddx = cx - ax;
        p0y[tid] = ay; p0x[tid] = ax;
        sdy[tid] = ddy; sdx[tid] = ddx;
        sidd[tid] = 1.0f / (ddy * ddy + ddx * ddx + 1e-8f);
    }
    __syncthreads();
    const int pix = chunk * 256 + tid;
    const float qy = (float)(pix >> 8);
    const float qx = (float)(pix & (WW - 1));
    float minr2 = 1e30f;
#pragma unroll 8
    for (int s = 0; s < NN; ++s) {
        float qpy = qy - p0y[s];
        float qpx = qx - p0x[s];
        float t = (qpy * sdy[s] + qpx * sdx[s]) * sidd[s];
        t = fminf(fmaxf(t, 0.0f), 1.0f);
        float ry = qpy - t * sdy[s];
        float rx = qpx - t * sdx[s];
        minr2 = fminf(minr2, ry * ry + rx * rx);
    }
    float dist = fminf(sqrtf(minr2 + 1e-12f), 15.0f);
    float e = pred[b * HH * WW + pix] - dist;
    float se = e * e;
    for (int off = 32; off > 0; off >>= 1) se += __shfl_down(se, off);
    __shared__ float red[4];
    if ((tid & 63) == 0) red[tid >> 6] = se;
    __syncthreads();
    __shared__ int lastBlk;
    if (tid == 0) {
        float p = (red[0] + red[1]) + (red[2] + red[3]);
        __hip_atomic_store(&partials[b * RBLK + chunk], p, __ATOMIC_RELEASE, __HIP_MEMORY_SCOPE_AGENT);
        int t = __hip_atomic_fetch_add(counter, 1, __ATOMIC_ACQ_REL, __HIP_MEMORY_SCOPE_AGENT);
        lastBlk = (t == NPART - 1);
    }
    __syncthreads();
    if (lastBlk) {
        float v = __hip_atomic_load(&partials[tid], __ATOMIC_RELAXED, __HIP_MEMORY_SCOPE_AGENT)
                + __hip_atomic_load(&partials[tid + 256], __ATOMIC_RELAXED, __HIP_MEMORY_SCOPE_AGENT);
        for (int off = 32; off > 0; off >>= 1) v += __shfl_down(v, off);
        __shared__ float red2[4];
        if ((tid & 63) == 0) red2[tid >> 6] = v;
        __syncthreads();
        if (tid == 0)
            out[0] = ((red2[0] + red2[1]) + (red2[2] + red2[3])) * (1.0f / (float)(NB * HH * WW));
    }
}

extern "C" void kernel_launch(void* const* d_in, const int* in_sizes, int n_in,
                              void* d_out, int out_size, void* d_ws, size_t ws_size,
                              hipStream_t stream) {
    const float* pred = (const float*)d_in[0];    // (B,1,H,W) f32
    const float* nodes = (const float*)d_in[1];   // (B,N,2) f32
    float* ws = (float*)d_ws;

    if (ws_size >= WS_NEEDED_BYTES) {
        fused3_kernel<<<dim3(NBLK), dim3(1024), 0, stream>>>(pred, nodes, ws, (float*)d_out);
    } else {
        float* partials = ws;                  // 512 f
        float* fnodes = ws + 512;              // 512 f
        int* counter = (int*)(ws + 1024);
        evolve_direct_kernel<<<dim3(NB), dim3(64), 0, stream>>>(pred, nodes, fnodes, counter);
        render_kernel<<<dim3(RBLK, NB), dim3(256), 0, stream>>>(pred, fnodes, partials,
                                                                counter, (float*)d_out);
    }
}

// Round 15
// 44.101 us; speedup vs baseline: 6.9751x; 1.0679x over previous
//
#include <hip/hip_runtime.h>

// Problem constants (match reference)
#define HH 256
#define WW 256
#define NB 2
#define NN 128
#define NSTEPS_K 50
#define NBLK 256                 // one block per CU -> co-residency guaranteed
#define MAGIC_G 0x11C0FFEE
#define MAGIC_E 0x22C0FFEE
#define MAGIC_R 0x33C0FFEE
#define MAGIC_X 0x5EC0DE00       // xcc publication tag (low byte = xcc id)
#define SPIN_G 400000
#define SPIN_E 120000
#define SPIN_R 120000

// ws float-offsets. ALL cross-block traffic via MALL-coherent relaxed atomics
// (R11: per-iteration acquire = invalidate storm; R12: per-block release =
// writeback storm). Flags reset in-kernel at end of every call.
#define WS_PART   0        // 256 floats  (per-block partials)
#define WS_GFLG   256      // 256 ints    (grad-done per block)
#define WS_RFLG   512      // 256 ints    (render-done per block)
#define WS_EREP   1024     // 16 slots * 64-int stride (evolve-done, 8 reps/batch)
#define WS_XCC    2048     // 2 ints      (evolve blocks' XCC id, tagged)
#define WS_FNODE  2112     // 256 u64 = 512 floats (final nodes)
#define WS_FIELD  4096     // NB*H*W float2 (1MB), 8B-aligned
#define WS_NEEDED_BYTES ((WS_FIELD + (size_t)NB * HH * WW * 2) * 4)

static __device__ __forceinline__ int ld_i(int* p) {
    return __hip_atomic_load(p, __ATOMIC_RELAXED, __HIP_MEMORY_SCOPE_AGENT);
}
static __device__ __forceinline__ void st_i(int* p, int v) {
    __hip_atomic_store(p, v, __ATOMIC_RELAXED, __HIP_MEMORY_SCOPE_AGENT);
}
static __device__ __forceinline__ unsigned long long ld_u64(unsigned long long* p) {
    return __hip_atomic_load(p, __ATOMIC_RELAXED, __HIP_MEMORY_SCOPE_AGENT);
}
static __device__ __forceinline__ void st_u64(unsigned long long* p, unsigned long long v) {
    __hip_atomic_store(p, v, __ATOMIC_RELAXED, __HIP_MEMORY_SCOPE_AGENT);
}
static __device__ __forceinline__ float ld_f(float* p) {
    return __hip_atomic_load(p, __ATOMIC_RELAXED, __HIP_MEMORY_SCOPE_AGENT);
}
static __device__ __forceinline__ void st_f(float* p, float v) {
    __hip_atomic_store(p, v, __ATOMIC_RELAXED, __HIP_MEMORY_SCOPE_AGENT);
}
union F2U { float2 f2; unsigned long long u; };

// 16B row-pair load at 8B alignment -> one global_load_dwordx4.
// r[0]=cell0.gy r[1]=cell0.gx r[2]=cell1.gy r[3]=cell1.gx (bit-identical use).
typedef float f4v __attribute__((ext_vector_type(4)));
static __device__ __forceinline__ f4v ld_pair(const float2* p) {
    f4v r;
    __builtin_memcpy(&r, p, sizeof(f4v));
    return r;
}

static __device__ __forceinline__ int read_xcc() {
    int xr;
    asm volatile("s_getreg_b32 %0, hwreg(HW_REG_XCC_ID)" : "=s"(xr));
    return xr & 0xFF;
}

__global__ __launch_bounds__(1024) void fused4_kernel(
        const float* __restrict__ pred,
        const float* __restrict__ nodes_in,
        float* __restrict__ ws,
        float* __restrict__ out) {
    float* partials = ws + WS_PART;
    int*   g_flags  = (int*)(ws + WS_GFLG);
    int*   r_flags  = (int*)(ws + WS_RFLG);
    int*   e_rep    = (int*)(ws + WS_EREP);
    int*   xcc_pub  = (int*)(ws + WS_XCC);
    unsigned long long* fnodes_u = (unsigned long long*)(ws + WS_FNODE);
    unsigned long long* field_u  = (unsigned long long*)(ws + WS_FIELD);
    const float2*       field_f2 = (const float2*)(ws + WS_FIELD);

    const int blk = blockIdx.x;     // 0..255
    const int tid = threadIdx.x;    // 0..1023
    const int myBatch = blk >> 7;   // pixel batch this block renders

    // Evolve blocks publish their XCD id FIRST (helpers target its L2).
    if (blk < NB && tid == 0) st_i(&xcc_pub[blk], MAGIC_X | read_xcc());

    // ========== Phase 1: gradient field via MALL atomics (512 cells/block) ===
    if (tid < 512) {
        int idx = blk * 512 + tid;          // 0 .. 131071
        int b = idx >> 16, p = idx & 0xFFFF;
        int i = p >> 8, j = p & (WW - 1);
        const float* f = pred + (b << 16);
        int iu = max(i - 1, 0), id = min(i + 1, HH - 1);
        int jl = max(j - 1, 0), jr = min(j + 1, WW - 1);
        float sy = (i == 0 || i == HH - 1) ? 1.0f : 0.5f;
        float sx = (j == 0 || j == WW - 1) ? 1.0f : 0.5f;
        F2U cv;
        cv.f2 = make_float2(sy * (f[(id << 8) + j] - f[(iu << 8) + j]),
                            sx * (f[(i << 8) + jr] - f[(i << 8) + jl]));
        st_u64(&field_u[idx], cv.u);        // -> MALL, no dirty L2 line
    }
    __syncthreads();                        // drains vmcnt pre-barrier
    if (tid == 0) st_i(&g_flags[blk], MAGIC_G);

    // ========== Phase 2a: sibling-XCD L2 warm (non-evolve blocks) =============
    if (blk >= NB) {
        const int myxcc = read_xcc();
        __shared__ int s_pub[NB];
        if (tid == 0) {
            #pragma unroll
            for (int b = 0; b < NB; ++b) {
                int pub = 0;
                for (int it = 0; it < 50000; ++it) {   // set at kernel entry
                    pub = ld_i(&xcc_pub[b]);
                    if ((pub & (int)0xFFFFFF00) == MAGIC_X) break;
                    __builtin_amdgcn_s_sleep(1);
                }
                s_pub[b] = pub;
            }
        }
        __syncthreads();
        #pragma unroll
        for (int b = 0; b < NB; ++b) {
            int pub = s_pub[b];                       // block-uniform
            if ((pub & (int)0xFFFFFF00) == MAGIC_X && (pub & 0xFF) == myxcc) {
                const int rank = (blk >> 3) & 31;     // distinct among siblings
                if (tid == 0) {                       // 4 producer slabs gate my chunk
                    #pragma unroll
                    for (int k = 0; k < 4; ++k) {
                        int* fl = &g_flags[b * 128 + rank * 4 + k];
                        for (int it = 0; it < SPIN_G; ++it) {
                            if (ld_i(fl) == MAGIC_G) break;
                            __builtin_amdgcn_s_sleep(1);
                        }
                    }
                }
                __syncthreads();
                if (tid < 256) {                      // warm 256 lines (8B/line)
                    int line = rank * 256 + tid;
                    float v = field_f2[(b << 16) + (line << 3)].x;
                    asm volatile("" :: "v"(v));
                }
            }
        }
    }

    // ========== Phase 2b: evolve (blocks 0..NB-1) =============================
    if (blk < NB) {
        const int b = blk;
        const float2* gb = field_f2 + (b << 16);

        if (tid < 64) {   // wave0 polls all 128 producer flags (2/lane)
            int f0 = b * 128 + tid * 2;
            for (int it = 0; it < SPIN_G; ++it) {
                bool ok = (ld_i(&g_flags[f0]) == MAGIC_G) &&
                          (ld_i(&g_flags[f0 + 1]) == MAGIC_G);
                if (__all(ok)) break;
                __builtin_amdgcn_s_sleep(1);
            }
        }
        __syncthreads();

        if (tid < 64) {
            const int l = tid;
            const int pl = (l + 63) & 63;
            const int nl = (l + 1) & 63;
            float4 nd = ((const float4*)nodes_in)[b * 64 + l];
            float y0n = nd.x, x0n = nd.y;      // node 2l
            float y1n = nd.z, x1n = nd.w;      // node 2l+1

            __builtin_amdgcn_s_setprio(1);
            for (int s = 0; s < NSTEPS_K; ++s) {
                // 4 x dwordx4 row-pair loads (sibling-warmed L2 hits)
                float yca = fminf(fmaxf(y0n, 0.0f), 254.999f);
                float xca = fminf(fmaxf(x0n, 0.0f), 254.999f);
                int ra = (int)yca, ca = (int)xca;
                float wya = yca - (float)ra, wxa = xca - (float)ca;
                int basea = (ra << 8) + ca;
                f4v ra0 = ld_pair(&gb[basea]);        // a00.gy a00.gx a01.gy a01.gx
                f4v ra1 = ld_pair(&gb[basea + WW]);   // a10.gy a10.gx a11.gy a11.gx

                float ycb = fminf(fmaxf(y1n, 0.0f), 254.999f);
                float xcb = fminf(fmaxf(x1n, 0.0f), 254.999f);
                int rb = (int)ycb, cb = (int)xcb;
                float wyb = ycb - (float)rb, wxb = xcb - (float)cb;
                int baseb = (rb << 8) + cb;
                f4v rb0 = ld_pair(&gb[baseb]);
                f4v rb1 = ld_pair(&gb[baseb + WW]);

                // single shuffle round: neighbor positions
                float pya = __shfl(y0n, pl), pxa = __shfl(x0n, pl);
                float pyb = __shfl(y1n, pl), pxb = __shfl(x1n, pl);
                float nya = __shfl(y0n, nl), nxa = __shfl(x0n, nl);
                float nyb = __shfl(y1n, nl), nxb = __shfl(x1n, nl);

                // d2[i] = (x[i+1] + x[i-1]) - 2 x[i]
                float d2ya = (y1n + pyb) - 2.0f * y0n;
                float d2xa = (x1n + pxb) - 2.0f * x0n;
                float d2yb = (nya + y0n) - 2.0f * y1n;
                float d2xb = (nxa + x0n) - 2.0f * x1n;
                float d2pyb = (y0n + pya) - 2.0f * pyb;
                float d2pxb = (x0n + pxa) - 2.0f * pxb;
                float d2nya = (nyb + y1n) - 2.0f * nya;
                float d2nxa = (nxb + x1n) - 2.0f * nxa;

                // d4[i] = (d2[i+1] + d2[i-1]) - 2 d2[i]
                float d4ya = (d2yb + d2pyb) - 2.0f * d2ya;
                float d4xa = (d2xb + d2pxb) - 2.0f * d2xa;
                float d4yb = (d2nya + d2ya) - 2.0f * d2yb;
                float d4xb = (d2nxa + d2xa) - 2.0f * d2xb;

                // bilerp (reference term order; component mapping unchanged)
                float ua = 1.0f - wya, va = 1.0f - wxa;
                float bya = ra0[0] * ua * va + ra0[2] * ua * wxa + ra1[0] * wya * va + ra1[2] * wya * wxa;
                float bxa = ra0[1] * ua * va + ra0[3] * ua * wxa + ra1[1] * wya * va + ra1[3] * wya * wxa;
                float ub = 1.0f - wyb, vb = 1.0f - wxb;
                float byb = rb0[0] * ub * vb + rb0[2] * ub * wxb + rb1[0] * wyb * vb + rb1[2] * wyb * wxb;
                float bxb = rb0[1] * ub * vb + rb0[3] * ub * wxb + rb1[1] * wyb * vb + rb1[3] * wyb * wxb;

                // x += STEPSZ*(ALPHA*d2 - BETA*d4 + ext); clip [0,255]
                y0n = y0n + 0.1f * ((0.01f * d2ya - 0.01f * d4ya) + (-10.0f * bya));
                x0n = x0n + 0.1f * ((0.01f * d2xa - 0.01f * d4xa) + (-10.0f * bxa));
                y1n = y1n + 0.1f * ((0.01f * d2yb - 0.01f * d4yb) + (-10.0f * byb));
                x1n = x1n + 0.1f * ((0.01f * d2xb - 0.01f * d4xb) + (-10.0f * bxb));
                y0n = fminf(fmaxf(y0n, 0.0f), 255.0f);
                x0n = fminf(fmaxf(x0n, 0.0f), 255.0f);
                y1n = fminf(fmaxf(y1n, 0.0f), 255.0f);
                x1n = fminf(fmaxf(x1n, 0.0f), 255.0f);
            }
            __builtin_amdgcn_s_setprio(0);

            // publish nodes via MALL atomics; vmcnt(0) orders flag AFTER data
            F2U c0, c1;
            c0.f2 = make_float2(y0n, x0n);
            c1.f2 = make_float2(y1n, x1n);
            st_u64(&fnodes_u[b * 128 + 2 * l], c0.u);
            st_u64(&fnodes_u[b * 128 + 2 * l + 1], c1.u);
            asm volatile("s_waitcnt vmcnt(0)" ::: "memory");
            if (l == 0) {
                #pragma unroll
                for (int k = 0; k < 8; ++k) st_i(&e_rep[(b * 8 + k) * 64], MAGIC_E);
            }
        }
        __syncthreads();
    }

    // ========== e-wait: only myBatch's flag, replicated lines =================
    if (tid == 0) {
        int* rep = &e_rep[(myBatch * 8 + (blk & 7)) * 64];
        for (int it = 0; it < SPIN_E; ++it) {
            if (ld_i(rep) == MAGIC_E) break;
            __builtin_amdgcn_s_sleep(8);
        }
    }
    __syncthreads();

    // ========== Phase 3: render (512 px/block, batch = myBatch) ===============
    __shared__ float nny[NN], nnx[NN];
    __shared__ float p0y[NN], p0x[NN], sdy[NN], sdx[NN], sidd[NN];
    if (tid < NN) {   // stage nodes via MALL atomic loads
        F2U cv; cv.u = ld_u64(&fnodes_u[myBatch * 128 + tid]);
        nny[tid] = cv.f2.x; nnx[tid] = cv.f2.y;
    }
    __syncthreads();
    if (tid < NN) {
        float ay = nny[tid], ax = nnx[tid];
        int j = (tid + 1) & (NN - 1);
        float cy = nny[j], cx = nnx[j];
        float ddy = cy - ay, ddx = cx - ax;
        p0y[tid] = ay; p0x[tid] = ax;
        sdy[tid] = ddy; sdx[tid] = ddx;
        sidd[tid] = 1.0f / (ddy * ddy + ddx * ddx + 1e-8f);
    }
    __syncthreads();

    float se = 0.0f;
    if (tid < 512) {
        int pixin = (blk & 127) * 512 + tid;    // 0 .. 65535 within batch
        float qy = (float)(pixin >> 8);
        float qx = (float)(pixin & (WW - 1));
        float minr2 = 1e30f;
        #pragma unroll 8
        for (int s = 0; s < NN; ++s) {
            float qpy = qy - p0y[s];
            float qpx = qx - p0x[s];
            float t = (qpy * sdy[s] + qpx * sdx[s]) * sidd[s];
            t = fminf(fmaxf(t, 0.0f), 1.0f);
            float ry = qpy - t * sdy[s];
            float rx = qpx - t * sdx[s];
            minr2 = fminf(minr2, ry * ry + rx * rx);
        }
        float dist = fminf(sqrtf(minr2 + 1e-12f), 15.0f);
        float e = pred[(myBatch << 16) + pixin] - dist;
        se = e * e;
    }
    for (int off = 32; off > 0; off >>= 1) se += __shfl_down(se, off);
    __shared__ float red[16];
    if ((tid & 63) == 0) red[tid >> 6] = se;   // waves 8..15 write 0
    __syncthreads();
    if (tid == 0) {
        float p = 0.0f;
        #pragma unroll
        for (int w = 0; w < 8; ++w) p += red[w];
        st_f(&partials[blk], p);
        asm volatile("s_waitcnt vmcnt(0)" ::: "memory");   // partial before flag
        st_i(&r_flags[blk], MAGIC_R);
    }

    // ========== Phase 4: finalize + flag reset (block 0) ======================
    if (blk == 0 && tid < 64) {
        for (int it = 0; it < SPIN_R; ++it) {
            bool ok = (ld_i(&r_flags[tid*4+0]) == MAGIC_R) &&
                      (ld_i(&r_flags[tid*4+1]) == MAGIC_R) &&
                      (ld_i(&r_flags[tid*4+2]) == MAGIC_R) &&
                      (ld_i(&r_flags[tid*4+3]) == MAGIC_R);
            if (__all(ok)) break;
            __builtin_amdgcn_s_sleep(8);
        }
        float s = 0.0f;
        #pragma unroll
        for (int k = 0; k < 4; ++k)   // fixed order -> deterministic
            s += ld_f(&partials[tid + (k << 6)]);
        for (int off = 32; off > 0; off >>= 1) s += __shfl_down(s, off);
        if (tid == 0) out[0] = s * (1.0f / (float)(NB * HH * WW));
        // reset flags (relaxed MALL stores; everyone is past their last read)
        #pragma unroll
        for (int k = 0; k < 4; ++k) { st_i(&g_flags[tid*4+k], 0); st_i(&r_flags[tid*4+k], 0); }
        if (tid < 16) st_i(&e_rep[tid * 64], 0);
        if (tid < NB) st_i(&xcc_pub[tid], 0);
    }
}

// ---------------- fallback (ws too small): 2-kernel path ---------------------
__device__ __forceinline__ void sample_grad_direct(const float* __restrict__ f,
                                                   float y, float x,
                                                   float& by, float& bx) {
    float yc = fminf(fmaxf(y, 0.0f), 254.999f);
    float xc = fminf(fmaxf(x, 0.0f), 254.999f);
    int r0 = (int)yc, c0 = (int)xc;
    int r1 = r0 + 1, c1 = c0 + 1;
    float wy = yc - (float)r0, wx = xc - (float)c0;
    int rm = max(r0 - 1, 0), rp = min(r1 + 1, HH - 1);
    int cm = max(c0 - 1, 0), cp = min(c1 + 1, WW - 1);
    float sy0 = (r0 == 0) ? 1.0f : 0.5f;
    float sy1 = (r1 == HH - 1) ? 1.0f : 0.5f;
    float sx0 = (c0 == 0) ? 1.0f : 0.5f;
    float sx1 = (c1 == WW - 1) ? 1.0f : 0.5f;
    const float* fr0 = f + (r0 << 8);
    const float* fr1 = f + (r1 << 8);
    const float* frm = f + (rm << 8);
    const float* frp = f + (rp << 8);
    float f00 = fr0[c0], f01 = fr0[c1];
    float f10 = fr1[c0], f11 = fr1[c1];
    float f0m = fr0[cm], f0p = fr0[cp];
    float f1m = fr1[cm], f1p = fr1[cp];
    float fm0 = frm[c0], fm1 = frm[c1];
    float fp0 = frp[c0], fp1 = frp[c1];
    float gy00 = sy0 * (f10 - fm0), gy01 = sy0 * (f11 - fm1);
    float gy10 = sy1 * (fp0 - f00), gy11 = sy1 * (fp1 - f01);
    float gx00 = sx0 * (f01 - f0m), gx01 = sx1 * (f0p - f00);
    float gx10 = sx0 * (f11 - f1m), gx11 = sx1 * (f1p - f10);
    float u = 1.0f - wy, v = 1.0f - wx;
    by = gy00 * u * v + gy01 * u * wx + gy10 * wy * v + gy11 * wy * wx;
    bx = gx00 * u * v + gx01 * u * wx + gx10 * wy * v + gx11 * wy * wx;
}

__global__ __launch_bounds__(64, 1) void evolve_direct_kernel(
        const float* __restrict__ pred,
        const float* __restrict__ nodes_in,
        float* __restrict__ nodes_out,
        int* __restrict__ counter) {
    const int b = blockIdx.x;
    const int l = threadIdx.x;
    if (b == 0 && l == 0)
        __hip_atomic_store(counter, 0, __ATOMIC_RELAXED, __HIP_MEMORY_SCOPE_AGENT);
    const float* f = pred + b * HH * WW;
    const int pl = (l + 63) & 63;
    const int nl = (l + 1) & 63;
    float4 nd = ((const float4*)nodes_in)[b * 64 + l];
    float y0n = nd.x, x0n = nd.y, y1n = nd.z, x1n = nd.w;
    for (int s = 0; s < NSTEPS_K; ++s) {
        float by0, bx0, by1, bx1;
        sample_grad_direct(f, y0n, x0n, by0, bx0);
        sample_grad_direct(f, y1n, x1n, by1, bx1);
        float pya = __shfl(y0n, pl), pxa = __shfl(x0n, pl);
        float pyb = __shfl(y1n, pl), pxb = __shfl(x1n, pl);
        float nya = __shfl(y0n, nl), nxa = __shfl(x0n, nl);
        float nyb = __shfl(y1n, nl), nxb = __shfl(x1n, nl);
        float d2ya = (y1n + pyb) - 2.0f * y0n;
        float d2xa = (x1n + pxb) - 2.0f * x0n;
        float d2yb = (nya + y0n) - 2.0f * y1n;
        float d2xb = (nxa + x0n) - 2.0f * x1n;
        float d2pyb = (y0n + pya) - 2.0f * pyb;
        float d2pxb = (x0n + pxa) - 2.0f * pxb;
        float d2nya = (nyb + y1n) - 2.0f * nya;
        float d2nxa = (nxb + x1n) - 2.0f * nxa;
        float d4ya = (d2yb + d2pyb) - 2.0f * d2ya;
        float d4xa = (d2xb + d2pxb) - 2.0f * d2xa;
        float d4yb = (d2nya + d2ya) - 2.0f * d2yb;
        float d4xb = (d2nxa + d2xa) - 2.0f * d2xb;
        y0n = y0n + 0.1f * ((0.01f * d2ya - 0.01f * d4ya) + (-10.0f * by0));
        x0n = x0n + 0.1f * ((0.01f * d2xa - 0.01f * d4xa) + (-10.0f * bx0));
        y1n = y1n + 0.1f * ((0.01f * d2yb - 0.01f * d4yb) + (-10.0f * by1));
        x1n = x1n + 0.1f * ((0.01f * d2xb - 0.01f * d4xb) + (-10.0f * bx1));
        y0n = fminf(fmaxf(y0n, 0.0f), 255.0f);
        x0n = fminf(fmaxf(x0n, 0.0f), 255.0f);
        y1n = fminf(fmaxf(y1n, 0.0f), 255.0f);
        x1n = fminf(fmaxf(x1n, 0.0f), 255.0f);
    }
    float4 o4; o4.x = y0n; o4.y = x0n; o4.z = y1n; o4.w = x1n;
    ((float4*)nodes_out)[b * 64 + l] = o4;
}

#define RBLK ((HH * WW) / 256)
#define NPART (NB * RBLK)

__global__ void render_kernel(const float* __restrict__ pred,
                              const float* __restrict__ nodes,
                              float* __restrict__ partials,
                              int* __restrict__ counter,
                              float* __restrict__ out) {
    const int b = blockIdx.y;
    const int chunk = blockIdx.x;
    const int tid = threadIdx.x;
    __shared__ float p0y[NN], p0x[NN], sdy[NN], sdx[NN], sidd[NN];
    if (tid < NN) {
        float ay = nodes[(b * NN + tid) * 2 + 0];
        float ax = nodes[(b * NN + tid) * 2 + 1];
        int j = (tid + 1) & (NN - 1);
        float cy = nodes[(b * NN + j) * 2 + 0];
        float cx = nodes[(b * NN + j) * 2 + 1];
        float ddy = cy - ay, ddx = cx - ax;
        p0y[tid] = ay; p0x[tid] = ax;
        sdy[tid] = ddy; sdx[tid] = ddx;
        sidd[tid] = 1.0f / (ddy * ddy + ddx * ddx + 1e-8f);
    }
    __syncthreads();
    const int pix = chunk * 256 + tid;
    const float qy = (float)(pix >> 8);
    const float qx = (float)(pix & (WW - 1));
    float minr2 = 1e30f;
#pragma unroll 8
    for (int s = 0; s < NN; ++s) {
        float qpy = qy - p0y[s];
        float qpx = qx - p0x[s];
        float t = (qpy * sdy[s] + qpx * sdx[s]) * sidd[s];
        t = fminf(fmaxf(t, 0.0f), 1.0f);
        float ry = qpy - t * sdy[s];
        float rx = qpx - t * sdx[s];
        minr2 = fminf(minr2, ry * ry + rx * rx);
    }
    float dist = fminf(sqrtf(minr2 + 1e-12f), 15.0f);
    float e = pred[b * HH * WW + pix] - dist;
    float se = e * e;
    for (int off = 32; off > 0; off >>= 1) se += __shfl_down(se, off);
    __shared__ float red[4];
    if ((tid & 63) == 0) red[tid >> 6] = se;
    __syncthreads();
    __shared__ int lastBlk;
    if (tid == 0) {
        float p = (red[0] + red[1]) + (red[2] + red[3]);
        __hip_atomic_store(&partials[b * RBLK + chunk], p, __ATOMIC_RELEASE, __HIP_MEMORY_SCOPE_AGENT);
        int t = __hip_atomic_fetch_add(counter, 1, __ATOMIC_ACQ_REL, __HIP_MEMORY_SCOPE_AGENT);
        lastBlk = (t == NPART - 1);
    }
    __syncthreads();
    if (lastBlk) {
        float v = __hip_atomic_load(&partials[tid], __ATOMIC_RELAXED, __HIP_MEMORY_SCOPE_AGENT)
                + __hip_atomic_load(&partials[tid + 256], __ATOMIC_RELAXED, __HIP_MEMORY_SCOPE_AGENT);
        for (int off = 32; off > 0; off >>= 1) v += __shfl_down(v, off);
        __shared__ float red2[4];
        if ((tid & 63) == 0) red2[tid >> 6] = v;
        __syncthreads();
        if (tid == 0)
            out[0] = ((red2[0] + red2[1]) + (red2[2] + red2[3])) * (1.0f / (float)(NB * HH * WW));
    }
}

extern "C" void kernel_launch(void* const* d_in, const int* in_sizes, int n_in,
                              void* d_out, int out_size, void* d_ws, size_t ws_size,
                              hipStream_t stream) {
    const float* pred = (const float*)d_in[0];    // (B,1,H,W) f32
    const float* nodes = (const float*)d_in[1];   // (B,N,2) f32
    float* ws = (float*)d_ws;

    if (ws_size >= WS_NEEDED_BYTES) {
        fused4_kernel<<<dim3(NBLK), dim3(1024), 0, stream>>>(pred, nodes, ws, (float*)d_out);
    } else {
        float* partials = ws;                  // 512 f
        float* fnodes = ws + 512;              // 512 f
        int* counter = (int*)(ws + 1024);
        evolve_direct_kernel<<<dim3(NB), dim3(64), 0, stream>>>(pred, nodes, fnodes, counter);
        render_kernel<<<dim3(RBLK, NB), dim3(256), 0, stream>>>(pred, fnodes, partials,
                                                                counter, (float*)d_out);
    }
}